// Round 2
// baseline (1515.158 us; speedup 1.0000x reference)
//
#include <hip/hip_runtime.h>
#include <math.h>

#define NN 10000
#define NE 80000
#define SF 97   // smF row stride (pad: 97%32==1 -> lanes spread across banks)
#define SX 68   // x/h row stride (68%4==0 keeps float4 alignment)
#define DEGCAP 64

// C[e][j] += sum_k x[e][k] * B[k][j]; lane=j, wave owns 16 e-rows (accums in regs).
__device__ __forceinline__ void gemm_tile(const float* __restrict__ xb,
                                          const float* __restrict__ Bs,
                                          float* __restrict__ acc,
                                          int j, int eb, int nk4) {
  #pragma unroll 1
  for (int kq = 0; kq < nk4; ++kq) {
    const int kk = kq * 4;
    const float w0 = Bs[(kk + 0) * 64 + j];
    const float w1 = Bs[(kk + 1) * 64 + j];
    const float w2 = Bs[(kk + 2) * 64 + j];
    const float w3 = Bs[(kk + 3) * 64 + j];
    #pragma unroll
    for (int m = 0; m < 16; ++m) {
      const float4 xv = *(const float4*)(xb + (eb + m) * SX + kk);
      float a = acc[m];
      a = fmaf(xv.x, w0, a);
      a = fmaf(xv.y, w1, a);
      a = fmaf(xv.z, w2, a);
      a = fmaf(xv.w, w3, a);
      acc[m] = a;
    }
  }
}

// ATOMIC=false: write per-edge c rows to ec[E][160] (fc 0..95 | sc 96..159).
// ATOMIC=true : legacy path, atomicAdd into fc_sum/sc_sum/cnt.
template<bool ATOMIC>
__global__ __launch_bounds__(256, 2)
void sgnn_edge(const float* __restrict__ f, const float* __restrict__ s,
               const float* __restrict__ edge_f, const float* __restrict__ edge_s,
               const float* __restrict__ Wemb,
               const float* __restrict__ W1, const float* __restrict__ b1,
               const float* __restrict__ W2, const float* __restrict__ b2,
               const float* __restrict__ W3, const float* __restrict__ b3,
               const int* __restrict__ eidx,
               float* __restrict__ ec_or_fc, float* __restrict__ sc_sum,
               float* __restrict__ cnt) {
  __shared__ float smF[64 * SF];
  __shared__ __align__(16) float xb[64 * SX];
  __shared__ float Bs[68 * 64];
  __shared__ float iFn[64];
  __shared__ float red[256];
  __shared__ int e0s[64], e1s[64];

  const int t = threadIdx.x;
  const int j = t & 63;
  const int w = t >> 6;
  const int eb = w * 16;
  const int bid = blockIdx.x;

  if (t < 64) {
    e0s[t] = eidx[bid * 64 + t];
    e1s[t] = eidx[NE + bid * 64 + t];
  }
  for (int idx = t; idx < 65 * 32; idx += 256) Bs[idx] = Wemb[idx];
  __syncthreads();

  // ---- embed: _f[le][i][:] = concat(f[e0],f[e1],edge_f)[i][:] @ Wemb1 ----
  #pragma unroll 1
  for (int r = 0; r < 24; ++r) {
    const int out = t + 256 * r;
    const int jj = out & 31;
    const int i = (out >> 5) % 3;
    const int le = out / 96;
    const float* base0 = f + e0s[le] * 96 + i * 32;
    const float* base1 = f + e1s[le] * 96 + i * 32;
    float a = 0.f;
    #pragma unroll
    for (int kq = 0; kq < 8; ++kq) {
      const float4 v = *(const float4*)(base0 + kq * 4);
      a = fmaf(v.x, Bs[(kq * 4 + 0) * 32 + jj], a);
      a = fmaf(v.y, Bs[(kq * 4 + 1) * 32 + jj], a);
      a = fmaf(v.z, Bs[(kq * 4 + 2) * 32 + jj], a);
      a = fmaf(v.w, Bs[(kq * 4 + 3) * 32 + jj], a);
    }
    #pragma unroll
    for (int kq = 0; kq < 8; ++kq) {
      const float4 v = *(const float4*)(base1 + kq * 4);
      a = fmaf(v.x, Bs[(32 + kq * 4 + 0) * 32 + jj], a);
      a = fmaf(v.y, Bs[(32 + kq * 4 + 1) * 32 + jj], a);
      a = fmaf(v.z, Bs[(32 + kq * 4 + 2) * 32 + jj], a);
      a = fmaf(v.w, Bs[(32 + kq * 4 + 3) * 32 + jj], a);
    }
    a = fmaf(edge_f[(bid * 64 + le) * 3 + i], Bs[64 * 32 + jj], a);
    smF[le * SF + i * 32 + jj] = a;
  }

  float acc[16];
  #pragma unroll
  for (int m = 0; m < 16; ++m) acc[m] = 0.f;
  float sumsq = 0.f;

  // ---- GEMM1 ----
  #pragma unroll 1
  for (int T = 0; T < 19; ++T) {
    const int wT = (T == 18) ? 68 : 64;
    const int kbase = T * 64;
    __syncthreads();
    #pragma unroll 1
    for (int m = 0; m < 17; ++m) {
      const int kk = w + m * 4;
      if (kk < wT) {
        float v;
        if (T < 16) {
          const int k = kbase + kk;
          const int a_ = k >> 5, b_ = k & 31;
          const float* fr = smF + j * SF;
          v = fmaf(fr[a_], fr[b_],
              fmaf(fr[32 + a_], fr[32 + b_], fr[64 + a_] * fr[64 + b_]));
          sumsq = fmaf(v, v, sumsq);
        } else if (T == 16) v = s[e0s[j] * 64 + kk];
        else if (T == 17)   v = s[e1s[j] * 64 + kk];
        else                v = edge_s[(bid * 64 + j) * 68 + kk];
        xb[j * SX + kk] = v;
        Bs[kk * 64 + j] = W1[(kbase + kk) * 64 + j];
      }
    }
    __syncthreads();
    gemm_tile(xb, Bs, acc, j, eb, wT >> 2);
  }

  __syncthreads();
  red[w * 64 + j] = sumsq;
  {
    const float bv = b1[j];
    #pragma unroll
    for (int m = 0; m < 16; ++m) {
      xb[(eb + m) * SX + j] = fmaxf(acc[m] + bv, 0.f);
      acc[m] = 0.f;
    }
  }
  #pragma unroll 1
  for (int m = 0; m < 16; ++m) {
    const int kk = w + m * 4;
    Bs[kk * 64 + j] = W2[kk * 64 + j];
  }
  __syncthreads();
  if (t < 64) {
    const float ss = red[t] + red[64 + t] + red[128 + t] + red[192 + t];
    iFn[t] = 1.f / (sqrtf(ss) + 1.f);
  }

  gemm_tile(xb, Bs, acc, j, eb, 16);
  __syncthreads();
  {
    const float bv = b2[j];
    #pragma unroll
    for (int m = 0; m < 16; ++m)
      xb[(eb + m) * SX + j] = fmaxf(acc[m] + bv, 0.f);
  }

  float fcp[48];
  #pragma unroll
  for (int q = 0; q < 48; ++q) fcp[q] = 0.f;

  #pragma unroll 1
  for (int nt = 0; nt < 17; ++nt) {
    const int n0 = nt * 64;
    __syncthreads();
    #pragma unroll 1
    for (int m = 0; m < 16; ++m) {
      const int kk = w + m * 4;
      Bs[kk * 64 + j] = W3[kk * 1088 + n0 + j];
    }
    __syncthreads();
    #pragma unroll
    for (int m = 0; m < 16; ++m) acc[m] = 0.f;
    gemm_tile(xb, Bs, acc, j, eb, 16);
    const float bv = b3[n0 + j];
    if (nt < 16) {
      const int a_ = nt * 2 + (j >> 5);
      #pragma unroll
      for (int m = 0; m < 16; ++m) {
        const float cv = (acc[m] + bv) * iFn[eb + m];
        const float* fr = smF + (eb + m) * SF;
        fcp[m * 3 + 0] = fmaf(fr[a_],      cv, fcp[m * 3 + 0]);
        fcp[m * 3 + 1] = fmaf(fr[32 + a_], cv, fcp[m * 3 + 1]);
        fcp[m * 3 + 2] = fmaf(fr[64 + a_], cv, fcp[m * 3 + 2]);
      }
    } else {
      #pragma unroll 1
      for (int m = 0; m < 16; ++m) {
        const float cv = (acc[m] + bv) * iFn[eb + m];
        if (ATOMIC) atomicAdd(sc_sum + e0s[eb + m] * 64 + j, cv);
        else        ec_or_fc[(size_t)(bid * 64 + eb + m) * 160 + 96 + j] = cv;
      }
    }
  }

  {
    const int b_ = j & 31;
    #pragma unroll 1
    for (int m = 0; m < 16; ++m) {
      const int el = eb + m;
      #pragma unroll
      for (int i = 0; i < 3; ++i) {
        float v = fcp[m * 3 + i];
        v += __shfl_xor(v, 32);
        if (j < 32) {
          if (ATOMIC) atomicAdd(ec_or_fc + e0s[el] * 96 + i * 32 + b_, v);
          else        ec_or_fc[(size_t)(bid * 64 + el) * 160 + i * 32 + b_] = v;
        }
      }
    }
  }
  if (ATOMIC && t < 64) atomicAdd(cnt + e0s[t], 1.0f);
}

// ---- path A: adjacency build + per-node mean gather ----
__global__ __launch_bounds__(256)
void sgnn_build(const int* __restrict__ eidx, int* __restrict__ deg,
                int* __restrict__ elist) {
  const int e = blockIdx.x * 256 + threadIdx.x;
  if (e < NE) {
    const int n = eidx[e];
    const int pos = atomicAdd(deg + n, 1);
    if (pos < DEGCAP) elist[n * DEGCAP + pos] = e;
  }
}

__global__ __launch_bounds__(256)
void sgnn_gather(const float* __restrict__ ec, const int* __restrict__ deg,
                 const int* __restrict__ elist,
                 float* __restrict__ fcm, float* __restrict__ scm) {
  const int w = threadIdx.x >> 6, j = threadIdx.x & 63;
  const int n = blockIdx.x * 4 + w;
  if (n >= NN) return;
  const int d = min(deg[n], DEGCAP);
  float a0 = 0.f, a1 = 0.f, a2 = 0.f;
  for (int k = 0; k < d; ++k) {
    const size_t e = (size_t)elist[n * DEGCAP + k];
    const float* r = ec + e * 160;
    a0 += r[j];
    a1 += r[64 + j];
    if (j < 32) a2 += r[128 + j];
  }
  const float ic = 1.f / fmaxf((float)deg[n], 1.f);
  a0 *= ic; a1 *= ic; a2 *= ic;
  fcm[n * 96 + j] = a0;
  if (j < 32) fcm[n * 96 + 64 + j] = a1;
  else        scm[n * 64 + (j - 32)] = a1;
  if (j < 32) scm[n * 64 + 32 + j] = a2;
}

// ---- path B fallback: in-place sums -> means ----
__global__ __launch_bounds__(256)
void sgnn_norm(float* __restrict__ fcm, float* __restrict__ scm,
               const float* __restrict__ cnt) {
  const int idx = blockIdx.x * 256 + threadIdx.x;
  if (idx >= NN * 160) return;
  const int n = idx / 160, c = idx % 160;
  const float ic = 1.f / fmaxf(cnt[n], 1.f);
  if (c < 96) fcm[n * 96 + c] *= ic;
  else        scm[n * 64 + (c - 96)] *= ic;
}

__global__ __launch_bounds__(256, 2)
void sgnn_node(const float* __restrict__ f, const float* __restrict__ s,
               const float* __restrict__ Wemb,
               const float* __restrict__ W1, const float* __restrict__ b1,
               const float* __restrict__ W2, const float* __restrict__ b2,
               const float* __restrict__ W3, const float* __restrict__ b3,
               const float* __restrict__ fcm, const float* __restrict__ scm,
               float* __restrict__ of, float* __restrict__ os) {
  __shared__ float smF[64 * SF];
  __shared__ __align__(16) float xb[64 * SX];
  __shared__ float Bs[68 * 64];
  __shared__ float iFn[64];
  __shared__ float red[256];

  const int t = threadIdx.x;
  const int j = t & 63;
  const int w = t >> 6;
  const int eb = w * 16;
  const int nbase = blockIdx.x * 64;

  for (int idx = t; idx < 64 * 32; idx += 256) Bs[idx] = Wemb[idx];
  __syncthreads();

  // ---- embed: tf = concat(f, f_c_mean) @ Wemb2 ----
  #pragma unroll 1
  for (int r = 0; r < 24; ++r) {
    const int out = t + 256 * r;
    const int jj = out & 31;
    const int i = (out >> 5) % 3;
    const int le = out / 96;
    const int nc = min(nbase + le, NN - 1);
    const float* base0 = f + nc * 96 + i * 32;
    const float* basec = fcm + nc * 96 + i * 32;
    float a = 0.f;
    #pragma unroll
    for (int kq = 0; kq < 8; ++kq) {
      const float4 v = *(const float4*)(base0 + kq * 4);
      a = fmaf(v.x, Bs[(kq * 4 + 0) * 32 + jj], a);
      a = fmaf(v.y, Bs[(kq * 4 + 1) * 32 + jj], a);
      a = fmaf(v.z, Bs[(kq * 4 + 2) * 32 + jj], a);
      a = fmaf(v.w, Bs[(kq * 4 + 3) * 32 + jj], a);
    }
    #pragma unroll
    for (int kq = 0; kq < 8; ++kq) {
      const float4 v = *(const float4*)(basec + kq * 4);
      a = fmaf(v.x, Bs[(32 + kq * 4 + 0) * 32 + jj], a);
      a = fmaf(v.y, Bs[(32 + kq * 4 + 1) * 32 + jj], a);
      a = fmaf(v.z, Bs[(32 + kq * 4 + 2) * 32 + jj], a);
      a = fmaf(v.w, Bs[(32 + kq * 4 + 3) * 32 + jj], a);
    }
    smF[le * SF + i * 32 + jj] = a;
  }

  float acc[16];
  #pragma unroll
  for (int m = 0; m < 16; ++m) acc[m] = 0.f;
  float sumsq = 0.f;

  #pragma unroll 1
  for (int T = 0; T < 18; ++T) {
    const int kbase = T * 64;
    __syncthreads();
    {
      const int nc = min(nbase + j, NN - 1);
      #pragma unroll 1
      for (int m = 0; m < 16; ++m) {
        const int kk = w + m * 4;
        float v;
        if (T < 16) {
          const int k = kbase + kk;
          const int a_ = k >> 5, b_ = k & 31;
          const float* fr = smF + j * SF;
          v = fmaf(fr[a_], fr[b_],
              fmaf(fr[32 + a_], fr[32 + b_], fr[64 + a_] * fr[64 + b_]));
          sumsq = fmaf(v, v, sumsq);
        } else if (T == 16) v = s[nc * 64 + kk];
        else                v = scm[nc * 64 + kk];
        xb[j * SX + kk] = v;
        Bs[kk * 64 + j] = W1[(kbase + kk) * 64 + j];
      }
    }
    __syncthreads();
    gemm_tile(xb, Bs, acc, j, eb, 16);
  }

  __syncthreads();
  red[w * 64 + j] = sumsq;
  {
    const float bv = b1[j];
    #pragma unroll
    for (int m = 0; m < 16; ++m) {
      xb[(eb + m) * SX + j] = fmaxf(acc[m] + bv, 0.f);
      acc[m] = 0.f;
    }
  }
  #pragma unroll 1
  for (int m = 0; m < 16; ++m) {
    const int kk = w + m * 4;
    Bs[kk * 64 + j] = W2[kk * 64 + j];
  }
  __syncthreads();
  if (t < 64) {
    const float ss = red[t] + red[64 + t] + red[128 + t] + red[192 + t];
    iFn[t] = 1.f / (sqrtf(ss) + 1.f);
  }

  gemm_tile(xb, Bs, acc, j, eb, 16);
  __syncthreads();
  {
    const float bv = b2[j];
    #pragma unroll
    for (int m = 0; m < 16; ++m)
      xb[(eb + m) * SX + j] = fmaxf(acc[m] + bv, 0.f);
  }

  float fcp[48];
  #pragma unroll
  for (int q = 0; q < 48; ++q) fcp[q] = 0.f;

  #pragma unroll 1
  for (int nt = 0; nt < 17; ++nt) {
    const int n0 = nt * 64;
    __syncthreads();
    #pragma unroll 1
    for (int m = 0; m < 16; ++m) {
      const int kk = w + m * 4;
      Bs[kk * 64 + j] = W3[kk * 1088 + n0 + j];
    }
    __syncthreads();
    #pragma unroll
    for (int m = 0; m < 16; ++m) acc[m] = 0.f;
    gemm_tile(xb, Bs, acc, j, eb, 16);
    const float bv = b3[n0 + j];
    if (nt < 16) {
      const int a_ = nt * 2 + (j >> 5);
      #pragma unroll
      for (int m = 0; m < 16; ++m) {
        const float cv = (acc[m] + bv) * iFn[eb + m];
        const float* fr = smF + (eb + m) * SF;
        fcp[m * 3 + 0] = fmaf(fr[a_],      cv, fcp[m * 3 + 0]);
        fcp[m * 3 + 1] = fmaf(fr[32 + a_], cv, fcp[m * 3 + 1]);
        fcp[m * 3 + 2] = fmaf(fr[64 + a_], cv, fcp[m * 3 + 2]);
      }
    } else {
      #pragma unroll 1
      for (int m = 0; m < 16; ++m) {
        const int n_m = nbase + eb + m;
        const float cv = (acc[m] + bv) * iFn[eb + m];
        if (n_m < NN) os[n_m * 64 + j] = cv + s[n_m * 64 + j];
      }
    }
  }

  {
    const int b_ = j & 31;
    #pragma unroll 1
    for (int m = 0; m < 16; ++m) {
      const int n_m = nbase + eb + m;
      #pragma unroll
      for (int i = 0; i < 3; ++i) {
        float v = fcp[m * 3 + i];
        v += __shfl_xor(v, 32);
        if (j < 32 && n_m < NN)
          of[n_m * 96 + i * 32 + b_] = v + f[n_m * 96 + i * 32 + b_];
      }
    }
  }
}

extern "C" void kernel_launch(void* const* d_in, const int* in_sizes, int n_in,
                              void* d_out, int out_size, void* d_ws, size_t ws_size,
                              hipStream_t stream) {
  const float* f      = (const float*)d_in[0];
  const float* s      = (const float*)d_in[1];
  const float* edge_f = (const float*)d_in[2];
  const float* edge_s = (const float*)d_in[3];
  const float* Wemb1  = (const float*)d_in[4];
  const float* nW1 = (const float*)d_in[5];
  const float* nb1 = (const float*)d_in[6];
  const float* nW2 = (const float*)d_in[7];
  const float* nb2 = (const float*)d_in[8];
  const float* nW3 = (const float*)d_in[9];
  const float* nb3 = (const float*)d_in[10];
  const float* Wemb2 = (const float*)d_in[11];
  const float* sW1 = (const float*)d_in[12];
  const float* sb1 = (const float*)d_in[13];
  const float* sW2 = (const float*)d_in[14];
  const float* sb2 = (const float*)d_in[15];
  const float* sW3 = (const float*)d_in[16];
  const float* sb3 = (const float*)d_in[17];
  const int* eidx  = (const int*)d_in[18];

  float* of = (float*)d_out;               // [NN*96]
  float* os = of + (size_t)NN * 96;        // [NN*64]

  // Path A layout: ec[NE*160] | fcm[NN*96] | scm[NN*64] | deg[NN] | elist[NN*64]
  const size_t needA = ((size_t)NE * 160 + (size_t)NN * 160) * 4
                     + (size_t)NN * 4 + (size_t)NN * DEGCAP * 4;

  if (ws_size >= needA) {
    float* ec  = (float*)d_ws;
    float* fcm = ec + (size_t)NE * 160;
    float* scm = fcm + (size_t)NN * 96;
    int*   deg = (int*)(scm + (size_t)NN * 64);
    int*   elist = deg + NN;

    hipMemsetAsync(deg, 0, (size_t)NN * 4, stream);
    hipLaunchKernelGGL(sgnn_edge<false>, dim3(NE / 64), dim3(256), 0, stream,
                       f, s, edge_f, edge_s, Wemb1,
                       nW1, nb1, nW2, nb2, nW3, nb3,
                       eidx, ec, nullptr, nullptr);
    hipLaunchKernelGGL(sgnn_build, dim3((NE + 255) / 256), dim3(256), 0, stream,
                       eidx, deg, elist);
    hipLaunchKernelGGL(sgnn_gather, dim3((NN + 3) / 4), dim3(256), 0, stream,
                       ec, deg, elist, fcm, scm);
    hipLaunchKernelGGL(sgnn_node, dim3((NN + 63) / 64), dim3(256), 0, stream,
                       f, s, Wemb2, sW1, sb1, sW2, sb2, sW3, sb3,
                       fcm, scm, of, os);
  } else {
    // Fallback: atomic accumulate (R0 path), then normalize in place.
    float* fcm = (float*)d_ws;                 // sums -> means
    float* scm = fcm + (size_t)NN * 96;
    float* cnt = scm + (size_t)NN * 64;
    hipMemsetAsync(d_ws, 0, (size_t)NN * 161 * 4, stream);
    hipLaunchKernelGGL(sgnn_edge<true>, dim3(NE / 64), dim3(256), 0, stream,
                       f, s, edge_f, edge_s, Wemb1,
                       nW1, nb1, nW2, nb2, nW3, nb3,
                       eidx, fcm, scm, cnt);
    hipLaunchKernelGGL(sgnn_norm, dim3((NN * 160 + 255) / 256), dim3(256), 0, stream,
                       fcm, scm, cnt);
    hipLaunchKernelGGL(sgnn_node, dim3((NN + 63) / 64), dim3(256), 0, stream,
                       f, s, Wemb2, sW1, sb1, sW2, sb2, sW3, sb3,
                       fcm, scm, of, os);
  }
}

// Round 3
// 1503.562 us; speedup vs baseline: 1.0077x; 1.0077x over previous
//
#include <hip/hip_runtime.h>
#include <math.h>

#define NN 10000
#define NE 80000
#define SF 97   // smF row stride (pad: spreads lanes across banks)
#define SX 68   // x/h row stride (float4-aligned)

// C[e][j] += sum_k x[e][k] * B[k][j]; lane=j, wave owns 16 e-rows (accums in regs).
__device__ __forceinline__ void gemm_tile(const float* __restrict__ xb,
                                          const float* __restrict__ Bs,
                                          float* __restrict__ acc,
                                          int j, int eb, int nk4) {
  #pragma unroll 1
  for (int kq = 0; kq < nk4; ++kq) {
    const int kk = kq * 4;
    const float w0 = Bs[(kk + 0) * 64 + j];
    const float w1 = Bs[(kk + 1) * 64 + j];
    const float w2 = Bs[(kk + 2) * 64 + j];
    const float w3 = Bs[(kk + 3) * 64 + j];
    #pragma unroll
    for (int m = 0; m < 16; ++m) {
      const float4 xv = *(const float4*)(xb + (eb + m) * SX + kk);
      float a = acc[m];
      a = fmaf(xv.x, w0, a);
      a = fmaf(xv.y, w1, a);
      a = fmaf(xv.z, w2, a);
      a = fmaf(xv.w, w3, a);
      acc[m] = a;
    }
  }
}

// ---- sort edges by e0: histogram -> scan -> scatter ----
__global__ __launch_bounds__(256)
void sgnn_hist(const int* __restrict__ eidx, int* __restrict__ deg) {
  const int e = blockIdx.x * 256 + threadIdx.x;
  if (e < NE) atomicAdd(deg + eidx[e], 1);
}

__global__ __launch_bounds__(1024)
void sgnn_scan(const int* __restrict__ deg, int* __restrict__ cursor) {
  __shared__ int sm[1024];
  __shared__ int carry;
  const int t = threadIdx.x;
  if (t == 0) carry = 0;
  __syncthreads();
  for (int base = 0; base < NN; base += 1024) {
    const int i = base + t;
    const int v = (i < NN) ? deg[i] : 0;
    sm[t] = v;
    __syncthreads();
    #pragma unroll
    for (int d = 1; d < 1024; d <<= 1) {
      const int add = (t >= d) ? sm[t - d] : 0;
      __syncthreads();
      sm[t] += add;
      __syncthreads();
    }
    const int excl = carry + sm[t] - v;
    if (i < NN) cursor[i] = excl;
    __syncthreads();
    if (t == 1023) carry += sm[1023];
    __syncthreads();
  }
}

__global__ __launch_bounds__(256)
void sgnn_scatter(const int* __restrict__ eidx, int* __restrict__ cursor,
                  int* __restrict__ sorted) {
  const int e = blockIdx.x * 256 + threadIdx.x;
  if (e < NE) {
    const int p = atomicAdd(cursor + eidx[e], 1);
    sorted[p] = e;
  }
}

// Edge pipeline on sorted edges; run-compressed atomics into fc_sum/sc_sum.
__global__ __launch_bounds__(256, 2)
void sgnn_edge(const float* __restrict__ f, const float* __restrict__ s,
               const float* __restrict__ edge_f, const float* __restrict__ edge_s,
               const float* __restrict__ Wemb,
               const float* __restrict__ W1, const float* __restrict__ b1,
               const float* __restrict__ W2, const float* __restrict__ b2,
               const float* __restrict__ W3, const float* __restrict__ b3,
               const int* __restrict__ eidx, const int* __restrict__ sorted,
               float* __restrict__ fc_sum, float* __restrict__ sc_sum) {
  __shared__ float smF[64 * SF];
  __shared__ __align__(16) float xb[64 * SX];
  __shared__ float Bs[68 * 64];
  __shared__ float iFn[64];
  __shared__ float red[256];
  __shared__ int es_s[64], e0s[64], e1s[64];

  const int t = threadIdx.x;
  const int j = t & 63;
  const int w = t >> 6;
  const int eb = w * 16;
  const int bid = blockIdx.x;

  if (t < 64) {
    const int e = sorted[bid * 64 + t];
    es_s[t] = e;
    e0s[t] = eidx[e];
    e1s[t] = eidx[NE + e];
  }
  for (int idx = t; idx < 65 * 32; idx += 256) Bs[idx] = Wemb[idx];
  __syncthreads();

  // ---- embed: _f[le][i][:] = concat(f[e0],f[e1],edge_f)[i][:] @ Wemb1 ----
  #pragma unroll 1
  for (int r = 0; r < 24; ++r) {
    const int out = t + 256 * r;
    const int jj = out & 31;
    const int i = (out >> 5) % 3;
    const int le = out / 96;
    const float* base0 = f + e0s[le] * 96 + i * 32;
    const float* base1 = f + e1s[le] * 96 + i * 32;
    float a = 0.f;
    #pragma unroll
    for (int kq = 0; kq < 8; ++kq) {
      const float4 v = *(const float4*)(base0 + kq * 4);
      a = fmaf(v.x, Bs[(kq * 4 + 0) * 32 + jj], a);
      a = fmaf(v.y, Bs[(kq * 4 + 1) * 32 + jj], a);
      a = fmaf(v.z, Bs[(kq * 4 + 2) * 32 + jj], a);
      a = fmaf(v.w, Bs[(kq * 4 + 3) * 32 + jj], a);
    }
    #pragma unroll
    for (int kq = 0; kq < 8; ++kq) {
      const float4 v = *(const float4*)(base1 + kq * 4);
      a = fmaf(v.x, Bs[(32 + kq * 4 + 0) * 32 + jj], a);
      a = fmaf(v.y, Bs[(32 + kq * 4 + 1) * 32 + jj], a);
      a = fmaf(v.z, Bs[(32 + kq * 4 + 2) * 32 + jj], a);
      a = fmaf(v.w, Bs[(32 + kq * 4 + 3) * 32 + jj], a);
    }
    a = fmaf(edge_f[es_s[le] * 3 + i], Bs[64 * 32 + jj], a);
    smF[le * SF + i * 32 + jj] = a;
  }

  float acc[16];
  #pragma unroll
  for (int m = 0; m < 16; ++m) acc[m] = 0.f;
  float sumsq = 0.f;

  // ---- GEMM1: h1 = x @ W1 ----
  #pragma unroll 1
  for (int T = 0; T < 19; ++T) {
    const int wT = (T == 18) ? 68 : 64;
    const int kbase = T * 64;
    __syncthreads();
    #pragma unroll 1
    for (int m = 0; m < 17; ++m) {
      const int kk = w + m * 4;
      if (kk < wT) {
        float v;
        if (T < 16) {
          const int k = kbase + kk;
          const int a_ = k >> 5, b_ = k & 31;
          const float* fr = smF + j * SF;
          v = fmaf(fr[a_], fr[b_],
              fmaf(fr[32 + a_], fr[32 + b_], fr[64 + a_] * fr[64 + b_]));
          sumsq = fmaf(v, v, sumsq);
        } else if (T == 16) v = s[e0s[j] * 64 + kk];
        else if (T == 17)   v = s[e1s[j] * 64 + kk];
        else                v = edge_s[es_s[j] * 68 + kk];
        xb[j * SX + kk] = v;
        Bs[kk * 64 + j] = W1[(kbase + kk) * 64 + j];
      }
    }
    __syncthreads();
    gemm_tile(xb, Bs, acc, j, eb, wT >> 2);
  }

  __syncthreads();
  red[w * 64 + j] = sumsq;
  {
    const float bv = b1[j];
    #pragma unroll
    for (int m = 0; m < 16; ++m) {
      xb[(eb + m) * SX + j] = fmaxf(acc[m] + bv, 0.f);
      acc[m] = 0.f;
    }
  }
  #pragma unroll 1
  for (int m = 0; m < 16; ++m) {
    const int kk = w + m * 4;
    Bs[kk * 64 + j] = W2[kk * 64 + j];
  }
  __syncthreads();
  if (t < 64) {
    const float ss = red[t] + red[64 + t] + red[128 + t] + red[192 + t];
    iFn[t] = 1.f / (sqrtf(ss) + 1.f);
  }

  // ---- GEMM2 ----
  gemm_tile(xb, Bs, acc, j, eb, 16);
  __syncthreads();
  {
    const float bv = b2[j];
    #pragma unroll
    for (int m = 0; m < 16; ++m)
      xb[(eb + m) * SX + j] = fmaxf(acc[m] + bv, 0.f);
  }

  // ---- GEMM3 + fused consume ----
  float fcp[48];
  #pragma unroll
  for (int q = 0; q < 48; ++q) fcp[q] = 0.f;

  #pragma unroll 1
  for (int nt = 0; nt < 17; ++nt) {
    const int n0 = nt * 64;
    __syncthreads();
    #pragma unroll 1
    for (int m = 0; m < 16; ++m) {
      const int kk = w + m * 4;
      Bs[kk * 64 + j] = W3[kk * 1088 + n0 + j];
    }
    __syncthreads();
    #pragma unroll
    for (int m = 0; m < 16; ++m) acc[m] = 0.f;
    gemm_tile(xb, Bs, acc, j, eb, 16);
    const float bv = b3[n0 + j];
    if (nt < 16) {
      const int a_ = nt * 2 + (j >> 5);
      #pragma unroll
      for (int m = 0; m < 16; ++m) {
        const float cv = (acc[m] + bv) * iFn[eb + m];
        const float* fr = smF + (eb + m) * SF;
        fcp[m * 3 + 0] = fmaf(fr[a_],      cv, fcp[m * 3 + 0]);
        fcp[m * 3 + 1] = fmaf(fr[32 + a_], cv, fcp[m * 3 + 1]);
        fcp[m * 3 + 2] = fmaf(fr[64 + a_], cv, fcp[m * 3 + 2]);
      }
    } else {
      // sc: run-compressed over sorted e0
      float run = 0.f;
      #pragma unroll 1
      for (int m = 0; m < 16; ++m) {
        run += (acc[m] + bv) * iFn[eb + m];
        const int e0 = e0s[eb + m];
        if (m == 15 || e0s[eb + m + 1] != e0) {
          atomicAdd(sc_sum + e0 * 64 + j, run);
          run = 0.f;
        }
      }
    }
  }

  // ---- fc: pair-reduce (j, j^32), run-compressed atomics ----
  {
    const int b_ = j & 31;
    float r0 = 0.f, r1 = 0.f, r2 = 0.f;
    #pragma unroll 1
    for (int m = 0; m < 16; ++m) {
      const int e0 = e0s[eb + m];
      float v0 = fcp[m * 3 + 0]; v0 += __shfl_xor(v0, 32);
      float v1 = fcp[m * 3 + 1]; v1 += __shfl_xor(v1, 32);
      float v2 = fcp[m * 3 + 2]; v2 += __shfl_xor(v2, 32);
      r0 += v0; r1 += v1; r2 += v2;
      if (m == 15 || e0s[eb + m + 1] != e0) {
        if (j < 32) {
          atomicAdd(fc_sum + e0 * 96 +      b_, r0);
          atomicAdd(fc_sum + e0 * 96 + 32 + b_, r1);
          atomicAdd(fc_sum + e0 * 96 + 64 + b_, r2);
        }
        r0 = r1 = r2 = 0.f;
      }
    }
  }
}

// sums -> means (deg from histogram; fcm/scm alias d_out)
__global__ __launch_bounds__(256)
void sgnn_norm(float* __restrict__ fcm, float* __restrict__ scm,
               const int* __restrict__ deg) {
  const int idx = blockIdx.x * 256 + threadIdx.x;
  if (idx >= NN * 160) return;
  const int n = idx / 160, c = idx % 160;
  const float ic = 1.f / fmaxf((float)deg[n], 1.f);
  if (c < 96) fcm[n * 96 + c] *= ic;
  else        scm[n * 64 + (c - 96)] *= ic;
}

__global__ __launch_bounds__(256, 2)
void sgnn_node(const float* __restrict__ f, const float* __restrict__ s,
               const float* __restrict__ Wemb,
               const float* __restrict__ W1, const float* __restrict__ b1,
               const float* __restrict__ W2, const float* __restrict__ b2,
               const float* __restrict__ W3, const float* __restrict__ b3,
               const float* __restrict__ fcm, const float* __restrict__ scm,
               float* __restrict__ of, float* __restrict__ os) {
  __shared__ float smF[64 * SF];
  __shared__ __align__(16) float xb[64 * SX];
  __shared__ float Bs[68 * 64];
  __shared__ float iFn[64];
  __shared__ float red[256];

  const int t = threadIdx.x;
  const int j = t & 63;
  const int w = t >> 6;
  const int eb = w * 16;
  const int nbase = blockIdx.x * 64;

  for (int idx = t; idx < 64 * 32; idx += 256) Bs[idx] = Wemb[idx];
  __syncthreads();

  // ---- embed: tf = concat(f, f_c_mean) @ Wemb2 ----
  #pragma unroll 1
  for (int r = 0; r < 24; ++r) {
    const int out = t + 256 * r;
    const int jj = out & 31;
    const int i = (out >> 5) % 3;
    const int le = out / 96;
    const int nc = min(nbase + le, NN - 1);
    const float* base0 = f + nc * 96 + i * 32;
    const float* basec = fcm + nc * 96 + i * 32;
    float a = 0.f;
    #pragma unroll
    for (int kq = 0; kq < 8; ++kq) {
      const float4 v = *(const float4*)(base0 + kq * 4);
      a = fmaf(v.x, Bs[(kq * 4 + 0) * 32 + jj], a);
      a = fmaf(v.y, Bs[(kq * 4 + 1) * 32 + jj], a);
      a = fmaf(v.z, Bs[(kq * 4 + 2) * 32 + jj], a);
      a = fmaf(v.w, Bs[(kq * 4 + 3) * 32 + jj], a);
    }
    #pragma unroll
    for (int kq = 0; kq < 8; ++kq) {
      const float4 v = *(const float4*)(basec + kq * 4);
      a = fmaf(v.x, Bs[(32 + kq * 4 + 0) * 32 + jj], a);
      a = fmaf(v.y, Bs[(32 + kq * 4 + 1) * 32 + jj], a);
      a = fmaf(v.z, Bs[(32 + kq * 4 + 2) * 32 + jj], a);
      a = fmaf(v.w, Bs[(32 + kq * 4 + 3) * 32 + jj], a);
    }
    smF[le * SF + i * 32 + jj] = a;
  }

  float acc[16];
  #pragma unroll
  for (int m = 0; m < 16; ++m) acc[m] = 0.f;
  float sumsq = 0.f;

  #pragma unroll 1
  for (int T = 0; T < 18; ++T) {
    const int kbase = T * 64;
    __syncthreads();
    {
      const int nc = min(nbase + j, NN - 1);
      #pragma unroll 1
      for (int m = 0; m < 16; ++m) {
        const int kk = w + m * 4;
        float v;
        if (T < 16) {
          const int k = kbase + kk;
          const int a_ = k >> 5, b_ = k & 31;
          const float* fr = smF + j * SF;
          v = fmaf(fr[a_], fr[b_],
              fmaf(fr[32 + a_], fr[32 + b_], fr[64 + a_] * fr[64 + b_]));
          sumsq = fmaf(v, v, sumsq);
        } else if (T == 16) v = s[nc * 64 + kk];
        else                v = scm[nc * 64 + kk];
        xb[j * SX + kk] = v;
        Bs[kk * 64 + j] = W1[(kbase + kk) * 64 + j];
      }
    }
    __syncthreads();
    gemm_tile(xb, Bs, acc, j, eb, 16);
  }

  __syncthreads();
  red[w * 64 + j] = sumsq;
  {
    const float bv = b1[j];
    #pragma unroll
    for (int m = 0; m < 16; ++m) {
      xb[(eb + m) * SX + j] = fmaxf(acc[m] + bv, 0.f);
      acc[m] = 0.f;
    }
  }
  #pragma unroll 1
  for (int m = 0; m < 16; ++m) {
    const int kk = w + m * 4;
    Bs[kk * 64 + j] = W2[kk * 64 + j];
  }
  __syncthreads();
  if (t < 64) {
    const float ss = red[t] + red[64 + t] + red[128 + t] + red[192 + t];
    iFn[t] = 1.f / (sqrtf(ss) + 1.f);
  }

  gemm_tile(xb, Bs, acc, j, eb, 16);
  __syncthreads();
  {
    const float bv = b2[j];
    #pragma unroll
    for (int m = 0; m < 16; ++m)
      xb[(eb + m) * SX + j] = fmaxf(acc[m] + bv, 0.f);
  }

  float fcp[48];
  #pragma unroll
  for (int q = 0; q < 48; ++q) fcp[q] = 0.f;

  #pragma unroll 1
  for (int nt = 0; nt < 17; ++nt) {
    const int n0 = nt * 64;
    __syncthreads();
    #pragma unroll 1
    for (int m = 0; m < 16; ++m) {
      const int kk = w + m * 4;
      Bs[kk * 64 + j] = W3[kk * 1088 + n0 + j];
    }
    __syncthreads();
    #pragma unroll
    for (int m = 0; m < 16; ++m) acc[m] = 0.f;
    gemm_tile(xb, Bs, acc, j, eb, 16);
    const float bv = b3[n0 + j];
    if (nt < 16) {
      const int a_ = nt * 2 + (j >> 5);
      #pragma unroll
      for (int m = 0; m < 16; ++m) {
        const float cv = (acc[m] + bv) * iFn[eb + m];
        const float* fr = smF + (eb + m) * SF;
        fcp[m * 3 + 0] = fmaf(fr[a_],      cv, fcp[m * 3 + 0]);
        fcp[m * 3 + 1] = fmaf(fr[32 + a_], cv, fcp[m * 3 + 1]);
        fcp[m * 3 + 2] = fmaf(fr[64 + a_], cv, fcp[m * 3 + 2]);
      }
    } else {
      #pragma unroll 1
      for (int m = 0; m < 16; ++m) {
        const int n_m = nbase + eb + m;
        const float cv = (acc[m] + bv) * iFn[eb + m];
        if (n_m < NN) os[n_m * 64 + j] = cv + s[n_m * 64 + j];
      }
    }
  }

  {
    const int b_ = j & 31;
    #pragma unroll 1
    for (int m = 0; m < 16; ++m) {
      const int n_m = nbase + eb + m;
      #pragma unroll
      for (int i = 0; i < 3; ++i) {
        float v = fcp[m * 3 + i];
        v += __shfl_xor(v, 32);
        if (j < 32 && n_m < NN)
          of[n_m * 96 + i * 32 + b_] = v + f[n_m * 96 + i * 32 + b_];
      }
    }
  }
}

extern "C" void kernel_launch(void* const* d_in, const int* in_sizes, int n_in,
                              void* d_out, int out_size, void* d_ws, size_t ws_size,
                              hipStream_t stream) {
  const float* f      = (const float*)d_in[0];
  const float* s      = (const float*)d_in[1];
  const float* edge_f = (const float*)d_in[2];
  const float* edge_s = (const float*)d_in[3];
  const float* Wemb1  = (const float*)d_in[4];
  const float* nW1 = (const float*)d_in[5];
  const float* nb1 = (const float*)d_in[6];
  const float* nW2 = (const float*)d_in[7];
  const float* nb2 = (const float*)d_in[8];
  const float* nW3 = (const float*)d_in[9];
  const float* nb3 = (const float*)d_in[10];
  const float* Wemb2 = (const float*)d_in[11];
  const float* sW1 = (const float*)d_in[12];
  const float* sb1 = (const float*)d_in[13];
  const float* sW2 = (const float*)d_in[14];
  const float* sb2 = (const float*)d_in[15];
  const float* sW3 = (const float*)d_in[16];
  const float* sb3 = (const float*)d_in[17];
  const int* eidx  = (const int*)d_in[18];

  float* of = (float*)d_out;               // [NN*96] ; aliases fc_mean
  float* os = of + (size_t)NN * 96;        // [NN*64] ; aliases sc_mean

  // ws: deg[NN] | cursor[NN] | sorted[NE]   (ints, ~400 KB)
  int* deg    = (int*)d_ws;
  int* cursor = deg + NN;
  int* sorted = cursor + NN;

  hipMemsetAsync(deg, 0, (size_t)NN * 4, stream);
  hipMemsetAsync(d_out, 0, (size_t)NN * 160 * 4, stream);

  hipLaunchKernelGGL(sgnn_hist, dim3((NE + 255) / 256), dim3(256), 0, stream,
                     eidx, deg);
  hipLaunchKernelGGL(sgnn_scan, dim3(1), dim3(1024), 0, stream, deg, cursor);
  hipLaunchKernelGGL(sgnn_scatter, dim3((NE + 255) / 256), dim3(256), 0, stream,
                     eidx, cursor, sorted);
  hipLaunchKernelGGL(sgnn_edge, dim3(NE / 64), dim3(256), 0, stream,
                     f, s, edge_f, edge_s, Wemb1,
                     nW1, nb1, nW2, nb2, nW3, nb3,
                     eidx, sorted, of /*fc_sum*/, os /*sc_sum*/);
  hipLaunchKernelGGL(sgnn_norm, dim3((NN * 160 + 255) / 256), dim3(256), 0, stream,
                     of, os, deg);
  hipLaunchKernelGGL(sgnn_node, dim3((NN + 63) / 64), dim3(256), 0, stream,
                     f, s, Wemb2, sW1, sb1, sW2, sb2, sW3, sb3,
                     of /*fcm*/, os /*scm*/, of, os);
}

// Round 4
// 574.482 us; speedup vs baseline: 2.6374x; 2.6172x over previous
//
#include <hip/hip_runtime.h>
#include <math.h>

#define NN 10000
#define NE 80000
#define SF 97    // smF row stride (f32)
#define STX 72   // bf16 tile row stride (144B rows, 16B-aligned)

typedef __attribute__((ext_vector_type(8))) __bf16 bf16x8;
typedef __attribute__((ext_vector_type(8))) short short8v;
typedef __attribute__((ext_vector_type(4))) float f32x4;

__device__ __forceinline__ ushort f2bf(float x) {
  union { float f; unsigned u; } v; v.f = x;
  unsigned r = v.u + 0x7FFFu + ((v.u >> 16) & 1u);
  return (ushort)(r >> 16);
}

// ---- sort edges by e0: histogram -> scan -> scatter (unchanged, verified) ----
__global__ __launch_bounds__(256)
void sgnn_hist(const int* __restrict__ eidx, int* __restrict__ deg) {
  const int e = blockIdx.x * 256 + threadIdx.x;
  if (e < NE) atomicAdd(deg + eidx[e], 1);
}

__global__ __launch_bounds__(1024)
void sgnn_scan(const int* __restrict__ deg, int* __restrict__ cursor) {
  __shared__ int sm[1024];
  __shared__ int carry;
  const int t = threadIdx.x;
  if (t == 0) carry = 0;
  __syncthreads();
  for (int base = 0; base < NN; base += 1024) {
    const int i = base + t;
    const int v = (i < NN) ? deg[i] : 0;
    sm[t] = v;
    __syncthreads();
    #pragma unroll
    for (int d = 1; d < 1024; d <<= 1) {
      const int add = (t >= d) ? sm[t - d] : 0;
      __syncthreads();
      sm[t] += add;
      __syncthreads();
    }
    const int excl = carry + sm[t] - v;
    if (i < NN) cursor[i] = excl;
    __syncthreads();
    if (t == 1023) carry += sm[1023];
    __syncthreads();
  }
}

__global__ __launch_bounds__(256)
void sgnn_scatter(const int* __restrict__ eidx, int* __restrict__ cursor,
                  int* __restrict__ sorted) {
  const int e = blockIdx.x * 256 + threadIdx.x;
  if (e < NE) {
    const int p = atomicAdd(cursor + eidx[e], 1);
    sorted[p] = e;
  }
}

// ---- one-shot weight convert: f32 -> blocked bf16 tiles [tile][c][k] ----
// tiles: 0..19 net_W1 (K=1220 pad 1280) | 20 net_W2 | 21..37 net_W3
//        38..55 self_W1 (K=1152)        | 56 self_W2 | 57..73 self_W3
__global__ __launch_bounds__(256)
void sgnn_wconv(const float* __restrict__ nW1, const float* __restrict__ nW2,
                const float* __restrict__ nW3, const float* __restrict__ sW1,
                const float* __restrict__ sW2, const float* __restrict__ sW3,
                ushort* __restrict__ wout) {
  const int gid = blockIdx.x * 256 + threadIdx.x;
  if (gid >= 74 * 4096) return;
  const int tile = gid >> 12, idx = gid & 4095;
  const int c = idx >> 6, k = idx & 63;
  float v;
  if (tile < 20)       { const int gk = tile * 64 + k; v = (gk < 1220) ? nW1[gk * 64 + c] : 0.f; }
  else if (tile == 20) { v = nW2[k * 64 + c]; }
  else if (tile < 38)  { v = nW3[k * 1088 + (tile - 21) * 64 + c]; }
  else if (tile < 56)  { const int gk = (tile - 38) * 64 + k; v = sW1[gk * 64 + c]; }
  else if (tile == 56) { v = sW2[k * 64 + c]; }
  else                 { v = sW3[k * 1088 + (tile - 57) * 64 + c]; }
  wout[gid] = f2bf(v);
}

#define STAGE_W(srcbase) do { const ushort* _s = (srcbase);                      \
  _Pragma("unroll") for (int rr = 0; rr < 2; ++rr) {                             \
    const int idx_ = t + 256 * rr; const int c_ = idx_ >> 3, ko_ = idx_ & 7;     \
    *(short8v*)&Wl[c_ * STX + ko_ * 8] = *(const short8v*)&_s[c_ * 64 + ko_ * 8];\
  } } while (0)

#define MFMA_K64() do {                                                          \
  _Pragma("unroll") for (int kb = 0; kb < 2; ++kb) {                             \
    const bf16x8 af_ = *(const bf16x8*)&Xl[(w * 16 + ll) * STX + kb * 32 + lh * 8]; \
    acc[0] = __builtin_amdgcn_mfma_f32_16x16x32_bf16(af_,                        \
        *(const bf16x8*)&Wl[(     ll) * STX + kb * 32 + lh * 8], acc[0], 0, 0, 0); \
    acc[1] = __builtin_amdgcn_mfma_f32_16x16x32_bf16(af_,                        \
        *(const bf16x8*)&Wl[(16 + ll) * STX + kb * 32 + lh * 8], acc[1], 0, 0, 0); \
    acc[2] = __builtin_amdgcn_mfma_f32_16x16x32_bf16(af_,                        \
        *(const bf16x8*)&Wl[(32 + ll) * STX + kb * 32 + lh * 8], acc[2], 0, 0, 0); \
    acc[3] = __builtin_amdgcn_mfma_f32_16x16x32_bf16(af_,                        \
        *(const bf16x8*)&Wl[(48 + ll) * STX + kb * 32 + lh * 8], acc[3], 0, 0, 0); \
  } } while (0)

#define ZERO_ACC() do { _Pragma("unroll") for (int q = 0; q < 4; ++q)            \
    acc[q] = (f32x4){0.f, 0.f, 0.f, 0.f}; } while (0)

__global__ __launch_bounds__(256, 2)
void sgnn_edge(const float* __restrict__ f, const float* __restrict__ s,
               const float* __restrict__ edge_f, const float* __restrict__ edge_s,
               const float* __restrict__ Wemb,
               const float* __restrict__ b1, const float* __restrict__ b2,
               const float* __restrict__ b3,
               const ushort* __restrict__ wbf,
               const int* __restrict__ eidx, const int* __restrict__ sorted,
               float* __restrict__ fc_sum, float* __restrict__ sc_sum) {
  __shared__ float smF[64 * SF];
  __shared__ ushort Xl[64 * STX];
  __shared__ ushort Wl[64 * STX];
  __shared__ float C2[64 * 65];       // doubles as Wemb1 staging (2080 <= 4160)
  __shared__ float red[256];
  __shared__ float iFn[64];
  __shared__ int es_s[64], e0s[64], e1s[64];

  const int t = threadIdx.x, j = t & 63, w = t >> 6, eb = w * 16;
  const int lh = j >> 4, ll = j & 15;
  const int bid = blockIdx.x;
  float* WembL = C2;

  if (t < 64) {
    const int e = sorted[bid * 64 + t];
    es_s[t] = e; e0s[t] = eidx[e]; e1s[t] = eidx[NE + e];
  }
  for (int idx = t; idx < 65 * 32; idx += 256) WembL[idx] = Wemb[idx];
  __syncthreads();

  // ---- embed (f32): smF[le][i*32+a] = concat(f[e0],f[e1],edge_f) @ Wemb1 ----
  #pragma unroll 1
  for (int r = 0; r < 24; ++r) {
    const int out = t + 256 * r;
    const int jj = out & 31;
    const int i = (out >> 5) % 3;
    const int le = out / 96;
    const float* base0 = f + e0s[le] * 96 + i * 32;
    const float* base1 = f + e1s[le] * 96 + i * 32;
    float a = 0.f;
    #pragma unroll
    for (int kq = 0; kq < 8; ++kq) {
      const float4 v = *(const float4*)(base0 + kq * 4);
      a = fmaf(v.x, WembL[(kq * 4 + 0) * 32 + jj], a);
      a = fmaf(v.y, WembL[(kq * 4 + 1) * 32 + jj], a);
      a = fmaf(v.z, WembL[(kq * 4 + 2) * 32 + jj], a);
      a = fmaf(v.w, WembL[(kq * 4 + 3) * 32 + jj], a);
    }
    #pragma unroll
    for (int kq = 0; kq < 8; ++kq) {
      const float4 v = *(const float4*)(base1 + kq * 4);
      a = fmaf(v.x, WembL[(32 + kq * 4 + 0) * 32 + jj], a);
      a = fmaf(v.y, WembL[(32 + kq * 4 + 1) * 32 + jj], a);
      a = fmaf(v.z, WembL[(32 + kq * 4 + 2) * 32 + jj], a);
      a = fmaf(v.w, WembL[(32 + kq * 4 + 3) * 32 + jj], a);
    }
    a = fmaf(edge_f[es_s[le] * 3 + i], WembL[64 * 32 + jj], a);
    smF[le * SF + i * 32 + jj] = a;
  }

  f32x4 acc[4];
  ZERO_ACC();
  float sumsq = 0.f;

  // ---- GEMM1: 20 K-stages of 64 ----
  #pragma unroll 1
  for (int T = 0; T < 20; ++T) {
    __syncthreads();
    {
      const float* fr = smF + j * SF;
      #pragma unroll 1
      for (int m = 0; m < 16; ++m) {
        const int kk = w + m * 4;
        float v;
        if (T < 16) {
          const int k = T * 64 + kk;
          const int a_ = k >> 5, b_ = k & 31;
          v = fmaf(fr[a_], fr[b_],
              fmaf(fr[32 + a_], fr[32 + b_], fr[64 + a_] * fr[64 + b_]));
          sumsq = fmaf(v, v, sumsq);
        } else if (T == 16) v = s[e0s[j] * 64 + kk];
        else if (T == 17)   v = s[e1s[j] * 64 + kk];
        else if (T == 18)   v = edge_s[es_s[j] * 68 + kk];
        else                v = (kk < 4) ? edge_s[es_s[j] * 68 + 64 + kk] : 0.f;
        Xl[j * STX + kk] = f2bf(v);
      }
    }
    STAGE_W(wbf + T * 4096);
    __syncthreads();
    MFMA_K64();
  }

  // ---- h1 epilogue + Fn reduce + W2 stage ----
  __syncthreads();
  red[w * 64 + j] = sumsq;
  #pragma unroll
  for (int nc = 0; nc < 4; ++nc) {
    const float bv = b1[nc * 16 + ll];
    #pragma unroll
    for (int r = 0; r < 4; ++r)
      Xl[(w * 16 + lh * 4 + r) * STX + nc * 16 + ll] = f2bf(fmaxf(acc[nc][r] + bv, 0.f));
  }
  STAGE_W(wbf + 20 * 4096);
  ZERO_ACC();
  __syncthreads();
  if (t < 64) {
    const float ss = red[t] + red[64 + t] + red[128 + t] + red[192 + t];
    iFn[t] = 1.f / (sqrtf(ss) + 1.f);
  }

  // ---- GEMM2 ----
  MFMA_K64();
  __syncthreads();
  #pragma unroll
  for (int nc = 0; nc < 4; ++nc) {
    const float bv = b2[nc * 16 + ll];
    #pragma unroll
    for (int r = 0; r < 4; ++r)
      Xl[(w * 16 + lh * 4 + r) * STX + nc * 16 + ll] = f2bf(fmaxf(acc[nc][r] + bv, 0.f));
  }

  // ---- GEMM3 (17 n-tiles) + fused consume ----
  float fcp[48];
  #pragma unroll
  for (int q = 0; q < 48; ++q) fcp[q] = 0.f;

  #pragma unroll 1
  for (int nt = 0; nt < 17; ++nt) {
    __syncthreads();
    STAGE_W(wbf + (21 + nt) * 4096);
    __syncthreads();
    ZERO_ACC();
    MFMA_K64();
    #pragma unroll
    for (int nc = 0; nc < 4; ++nc)
      #pragma unroll
      for (int r = 0; r < 4; ++r)
        C2[(w * 16 + lh * 4 + r) * 65 + nc * 16 + ll] = acc[nc][r];
    // wave-private rows: no barrier needed before consume
    const float bv = b3[nt * 64 + j];
    if (nt < 16) {
      const int a_ = nt * 2 + (j >> 5);
      #pragma unroll
      for (int m = 0; m < 16; ++m) {
        const float cv = (C2[(eb + m) * 65 + j] + bv) * iFn[eb + m];
        const float* fr = smF + (eb + m) * SF;
        fcp[m * 3 + 0] = fmaf(fr[a_],      cv, fcp[m * 3 + 0]);
        fcp[m * 3 + 1] = fmaf(fr[32 + a_], cv, fcp[m * 3 + 1]);
        fcp[m * 3 + 2] = fmaf(fr[64 + a_], cv, fcp[m * 3 + 2]);
      }
    } else {
      float run = 0.f;
      #pragma unroll 1
      for (int m = 0; m < 16; ++m) {
        run += (C2[(eb + m) * 65 + j] + bv) * iFn[eb + m];
        const int e0 = e0s[eb + m];
        if (m == 15 || e0s[eb + m + 1] != e0) {
          atomicAdd(sc_sum + e0 * 64 + j, run);
          run = 0.f;
        }
      }
    }
  }

  // ---- fc: pair-reduce (j, j^32), run-compressed atomics ----
  {
    const int b_ = j & 31;
    float r0 = 0.f, r1 = 0.f, r2 = 0.f;
    #pragma unroll 1
    for (int m = 0; m < 16; ++m) {
      const int e0 = e0s[eb + m];
      float v0 = fcp[m * 3 + 0]; v0 += __shfl_xor(v0, 32);
      float v1 = fcp[m * 3 + 1]; v1 += __shfl_xor(v1, 32);
      float v2 = fcp[m * 3 + 2]; v2 += __shfl_xor(v2, 32);
      r0 += v0; r1 += v1; r2 += v2;
      if (m == 15 || e0s[eb + m + 1] != e0) {
        if (j < 32) {
          atomicAdd(fc_sum + e0 * 96 +      b_, r0);
          atomicAdd(fc_sum + e0 * 96 + 32 + b_, r1);
          atomicAdd(fc_sum + e0 * 96 + 64 + b_, r2);
        }
        r0 = r1 = r2 = 0.f;
      }
    }
  }
}

// sums -> means
__global__ __launch_bounds__(256)
void sgnn_norm(float* __restrict__ fcm, float* __restrict__ scm,
               const int* __restrict__ deg) {
  const int idx = blockIdx.x * 256 + threadIdx.x;
  if (idx >= NN * 160) return;
  const int n = idx / 160, c = idx % 160;
  const float ic = 1.f / fmaxf((float)deg[n], 1.f);
  if (c < 96) fcm[n * 96 + c] *= ic;
  else        scm[n * 64 + (c - 96)] *= ic;
}

__global__ __launch_bounds__(256, 2)
void sgnn_node(const float* __restrict__ f, const float* __restrict__ s,
               const float* __restrict__ Wemb,
               const float* __restrict__ b1, const float* __restrict__ b2,
               const float* __restrict__ b3,
               const ushort* __restrict__ wbf,
               const float* __restrict__ fcm, const float* __restrict__ scm,
               float* __restrict__ of, float* __restrict__ os) {
  __shared__ float smF[64 * SF];
  __shared__ ushort Xl[64 * STX];
  __shared__ ushort Wl[64 * STX];
  __shared__ float C2[64 * 65];
  __shared__ float red[256];
  __shared__ float iFn[64];

  const int t = threadIdx.x, j = t & 63, w = t >> 6, eb = w * 16;
  const int lh = j >> 4, ll = j & 15;
  const int nbase = blockIdx.x * 64;
  float* WembL = C2;

  for (int idx = t; idx < 64 * 32; idx += 256) WembL[idx] = Wemb[idx];
  __syncthreads();

  // ---- embed: tf = concat(f, f_c_mean) @ Wemb2 ----
  #pragma unroll 1
  for (int r = 0; r < 24; ++r) {
    const int out = t + 256 * r;
    const int jj = out & 31;
    const int i = (out >> 5) % 3;
    const int le = out / 96;
    const int nc = min(nbase + le, NN - 1);
    const float* base0 = f + nc * 96 + i * 32;
    const float* basec = fcm + nc * 96 + i * 32;
    float a = 0.f;
    #pragma unroll
    for (int kq = 0; kq < 8; ++kq) {
      const float4 v = *(const float4*)(base0 + kq * 4);
      a = fmaf(v.x, WembL[(kq * 4 + 0) * 32 + jj], a);
      a = fmaf(v.y, WembL[(kq * 4 + 1) * 32 + jj], a);
      a = fmaf(v.z, WembL[(kq * 4 + 2) * 32 + jj], a);
      a = fmaf(v.w, WembL[(kq * 4 + 3) * 32 + jj], a);
    }
    #pragma unroll
    for (int kq = 0; kq < 8; ++kq) {
      const float4 v = *(const float4*)(basec + kq * 4);
      a = fmaf(v.x, WembL[(32 + kq * 4 + 0) * 32 + jj], a);
      a = fmaf(v.y, WembL[(32 + kq * 4 + 1) * 32 + jj], a);
      a = fmaf(v.z, WembL[(32 + kq * 4 + 2) * 32 + jj], a);
      a = fmaf(v.w, WembL[(32 + kq * 4 + 3) * 32 + jj], a);
    }
    smF[le * SF + i * 32 + jj] = a;
  }

  f32x4 acc[4];
  ZERO_ACC();
  float sumsq = 0.f;

  // ---- GEMM1: 18 K-stages ----
  #pragma unroll 1
  for (int T = 0; T < 18; ++T) {
    __syncthreads();
    {
      const int nc = min(nbase + j, NN - 1);
      const float* fr = smF + j * SF;
      #pragma unroll 1
      for (int m = 0; m < 16; ++m) {
        const int kk = w + m * 4;
        float v;
        if (T < 16) {
          const int k = T * 64 + kk;
          const int a_ = k >> 5, b_ = k & 31;
          v = fmaf(fr[a_], fr[b_],
              fmaf(fr[32 + a_], fr[32 + b_], fr[64 + a_] * fr[64 + b_]));
          sumsq = fmaf(v, v, sumsq);
        } else if (T == 16) v = s[nc * 64 + kk];
        else                v = scm[nc * 64 + kk];
        Xl[j * STX + kk] = f2bf(v);
      }
    }
    STAGE_W(wbf + (38 + T) * 4096);
    __syncthreads();
    MFMA_K64();
  }

  __syncthreads();
  red[w * 64 + j] = sumsq;
  #pragma unroll
  for (int nc = 0; nc < 4; ++nc) {
    const float bv = b1[nc * 16 + ll];
    #pragma unroll
    for (int r = 0; r < 4; ++r)
      Xl[(w * 16 + lh * 4 + r) * STX + nc * 16 + ll] = f2bf(fmaxf(acc[nc][r] + bv, 0.f));
  }
  STAGE_W(wbf + 56 * 4096);
  ZERO_ACC();
  __syncthreads();
  if (t < 64) {
    const float ss = red[t] + red[64 + t] + red[128 + t] + red[192 + t];
    iFn[t] = 1.f / (sqrtf(ss) + 1.f);
  }

  MFMA_K64();
  __syncthreads();
  #pragma unroll
  for (int nc = 0; nc < 4; ++nc) {
    const float bv = b2[nc * 16 + ll];
    #pragma unroll
    for (int r = 0; r < 4; ++r)
      Xl[(w * 16 + lh * 4 + r) * STX + nc * 16 + ll] = f2bf(fmaxf(acc[nc][r] + bv, 0.f));
  }

  float fcp[48];
  #pragma unroll
  for (int q = 0; q < 48; ++q) fcp[q] = 0.f;

  #pragma unroll 1
  for (int nt = 0; nt < 17; ++nt) {
    __syncthreads();
    STAGE_W(wbf + (57 + nt) * 4096);
    __syncthreads();
    ZERO_ACC();
    MFMA_K64();
    #pragma unroll
    for (int nc = 0; nc < 4; ++nc)
      #pragma unroll
      for (int r = 0; r < 4; ++r)
        C2[(w * 16 + lh * 4 + r) * 65 + nc * 16 + ll] = acc[nc][r];
    const float bv = b3[nt * 64 + j];
    if (nt < 16) {
      const int a_ = nt * 2 + (j >> 5);
      #pragma unroll
      for (int m = 0; m < 16; ++m) {
        const float cv = (C2[(eb + m) * 65 + j] + bv) * iFn[eb + m];
        const float* fr = smF + (eb + m) * SF;
        fcp[m * 3 + 0] = fmaf(fr[a_],      cv, fcp[m * 3 + 0]);
        fcp[m * 3 + 1] = fmaf(fr[32 + a_], cv, fcp[m * 3 + 1]);
        fcp[m * 3 + 2] = fmaf(fr[64 + a_], cv, fcp[m * 3 + 2]);
      }
    } else {
      #pragma unroll 1
      for (int m = 0; m < 16; ++m) {
        const int n_m = nbase + eb + m;
        const float cv = (C2[(eb + m) * 65 + j] + bv) * iFn[eb + m];
        if (n_m < NN) os[n_m * 64 + j] = cv + s[n_m * 64 + j];
      }
    }
  }

  {
    const int b_ = j & 31;
    #pragma unroll 1
    for (int m = 0; m < 16; ++m) {
      const int n_m = nbase + eb + m;
      #pragma unroll
      for (int i = 0; i < 3; ++i) {
        float v = fcp[m * 3 + i];
        v += __shfl_xor(v, 32);
        if (j < 32 && n_m < NN)
          of[n_m * 96 + i * 32 + b_] = v + f[n_m * 96 + i * 32 + b_];
      }
    }
  }
}

extern "C" void kernel_launch(void* const* d_in, const int* in_sizes, int n_in,
                              void* d_out, int out_size, void* d_ws, size_t ws_size,
                              hipStream_t stream) {
  const float* f      = (const float*)d_in[0];
  const float* s      = (const float*)d_in[1];
  const float* edge_f = (const float*)d_in[2];
  const float* edge_s = (const float*)d_in[3];
  const float* Wemb1  = (const float*)d_in[4];
  const float* nW1 = (const float*)d_in[5];
  const float* nb1 = (const float*)d_in[6];
  const float* nW2 = (const float*)d_in[7];
  const float* nb2 = (const float*)d_in[8];
  const float* nW3 = (const float*)d_in[9];
  const float* nb3 = (const float*)d_in[10];
  const float* Wemb2 = (const float*)d_in[11];
  const float* sW1 = (const float*)d_in[12];
  const float* sb1 = (const float*)d_in[13];
  const float* sW2 = (const float*)d_in[14];
  const float* sb2 = (const float*)d_in[15];
  const float* sW3 = (const float*)d_in[16];
  const float* sb3 = (const float*)d_in[17];
  const int* eidx  = (const int*)d_in[18];

  float* of = (float*)d_out;               // [NN*96] ; aliases fc mean
  float* os = of + (size_t)NN * 96;        // [NN*64] ; aliases sc mean

  // ws: deg[NN] | cursor[NN] | sorted[NE] | wbf[74*4096 bf16]  (~1.0 MB)
  int* deg    = (int*)d_ws;
  int* cursor = deg + NN;
  int* sorted = cursor + NN;
  ushort* wbf = (ushort*)(sorted + NE);

  hipMemsetAsync(deg, 0, (size_t)NN * 4, stream);
  hipMemsetAsync(d_out, 0, (size_t)NN * 160 * 4, stream);

  hipLaunchKernelGGL(sgnn_wconv, dim3((74 * 4096 + 255) / 256), dim3(256), 0, stream,
                     nW1, nW2, nW3, sW1, sW2, sW3, wbf);
  hipLaunchKernelGGL(sgnn_hist, dim3((NE + 255) / 256), dim3(256), 0, stream,
                     eidx, deg);
  hipLaunchKernelGGL(sgnn_scan, dim3(1), dim3(1024), 0, stream, deg, cursor);
  hipLaunchKernelGGL(sgnn_scatter, dim3((NE + 255) / 256), dim3(256), 0, stream,
                     eidx, cursor, sorted);
  hipLaunchKernelGGL(sgnn_edge, dim3(NE / 64), dim3(256), 0, stream,
                     f, s, edge_f, edge_s, Wemb1, nb1, nb2, nb3,
                     wbf, eidx, sorted, of /*fc_sum*/, os /*sc_sum*/);
  hipLaunchKernelGGL(sgnn_norm, dim3((NN * 160 + 255) / 256), dim3(256), 0, stream,
                     of, os, deg);
  hipLaunchKernelGGL(sgnn_node, dim3((NN + 63) / 64), dim3(256), 0, stream,
                     f, s, Wemb2, sb1, sb2, sb3,
                     wbf, of /*fcm*/, os /*scm*/, of, os);
}

// Round 5
// 464.117 us; speedup vs baseline: 3.2646x; 1.2378x over previous
//
#include <hip/hip_runtime.h>
#include <math.h>

#define NN 10000
#define NE 80000
#define SF 97    // smF row stride (f32): stride%32==1 -> conflict-free per-lane rows
#define STX 72   // bf16 tile row stride (144B rows, 16B-aligned)
#define NTRI 528 // 32*33/2 unique Gram entries

typedef __attribute__((ext_vector_type(8))) __bf16 bf16x8;
typedef __attribute__((ext_vector_type(8))) short short8v;
typedef __attribute__((ext_vector_type(4))) float f32x4;

__device__ __forceinline__ ushort f2bf(float x) {
  union { float f; unsigned u; } v; v.f = x;
  unsigned r = v.u + 0x7FFFu + ((v.u >> 16) & 1u);
  return (ushort)(r >> 16);
}
__device__ __forceinline__ float bf2f(ushort u) {
  union { unsigned u; float f; } v; v.u = (unsigned)u << 16;
  return v.f;
}
// tri index k -> (a,b), a<=b, a-major enumeration
__device__ __forceinline__ void tri_ab(int k, int& a, int& b) {
  int aa = 0, rem = k;
  while (rem >= 32 - aa) { rem -= 32 - aa; ++aa; }
  a = aa; b = aa + rem;
}

// ---- sort edges by e0 (verified R2/R3) ----
__global__ __launch_bounds__(256)
void sgnn_hist(const int* __restrict__ eidx, int* __restrict__ deg) {
  const int e = blockIdx.x * 256 + threadIdx.x;
  if (e < NE) atomicAdd(deg + eidx[e], 1);
}

__global__ __launch_bounds__(1024)
void sgnn_scan(const int* __restrict__ deg, int* __restrict__ cursor) {
  __shared__ int sm[1024];
  __shared__ int carry;
  const int t = threadIdx.x;
  if (t == 0) carry = 0;
  __syncthreads();
  for (int base = 0; base < NN; base += 1024) {
    const int i = base + t;
    const int v = (i < NN) ? deg[i] : 0;
    sm[t] = v;
    __syncthreads();
    #pragma unroll
    for (int d = 1; d < 1024; d <<= 1) {
      const int add = (t >= d) ? sm[t - d] : 0;
      __syncthreads();
      sm[t] += add;
      __syncthreads();
    }
    const int excl = carry + sm[t] - v;
    if (i < NN) cursor[i] = excl;
    __syncthreads();
    if (t == 1023) carry += sm[1023];
    __syncthreads();
  }
}

__global__ __launch_bounds__(256)
void sgnn_scatter(const int* __restrict__ eidx, int* __restrict__ cursor,
                  int* __restrict__ sorted) {
  const int e = blockIdx.x * 256 + threadIdx.x;
  if (e < NE) {
    const int p = atomicAdd(cursor + eidx[e], 1);
    sorted[p] = e;
  }
}

// ---- weight convert: f32 -> blocked bf16 [tile][c][k], W1 K-folded symmetric ----
// net: 0..11 W1f (K: 528 tri | stage8 tail edge_s[64..67] | s0 | s1 | edge_s[0..63])
//      12 W2 | 13..29 W3
// self: 30..40 W1f (tri | s | s_c) | 41 W2 | 42..58 W3
// tab[528] appended: a | b<<8 | (a!=b)<<15
__global__ __launch_bounds__(256)
void sgnn_wconv(const float* __restrict__ nW1, const float* __restrict__ nW2,
                const float* __restrict__ nW3, const float* __restrict__ sW1,
                const float* __restrict__ sW2, const float* __restrict__ sW3,
                ushort* __restrict__ wout, ushort* __restrict__ tab) {
  const int gid = blockIdx.x * 256 + threadIdx.x;
  if (gid >= 59 * 4096) {
    const int k = gid - 59 * 4096;
    if (k < NTRI) {
      int a, b; tri_ab(k, a, b);
      tab[k] = (ushort)(a | (b << 8) | ((a != b) ? 0x8000 : 0));
    }
    return;
  }
  const int tile = gid >> 12, idx = gid & 4095;
  const int c = idx >> 6, k = idx & 63;
  float v = 0.f;
  if (tile < 12) {
    const int T = tile;
    if (T < 8 || (T == 8 && k < 16)) {
      const int ktri = T * 64 + k;
      if (ktri < NTRI) {
        int a, b; tri_ab(ktri, a, b);
        v = nW1[(a * 32 + b) * 64 + c];
        if (a != b) v += nW1[(b * 32 + a) * 64 + c];
      }
    } else if (T == 8) { if (k < 20) v = nW1[(1216 + (k - 16)) * 64 + c]; }
    else if (T == 9)   v = nW1[(1024 + k) * 64 + c];
    else if (T == 10)  v = nW1[(1088 + k) * 64 + c];
    else               v = nW1[(1152 + k) * 64 + c];
  } else if (tile == 12) v = nW2[k * 64 + c];
  else if (tile < 30)    v = nW3[k * 1088 + (tile - 13) * 64 + c];
  else if (tile < 41) {
    const int T = tile - 30;
    if (T < 8 || (T == 8 && k < 16)) {
      const int ktri = T * 64 + k;
      if (ktri < NTRI) {
        int a, b; tri_ab(ktri, a, b);
        v = sW1[(a * 32 + b) * 64 + c];
        if (a != b) v += sW1[(b * 32 + a) * 64 + c];
      }
    } else if (T == 9) v = sW1[(1024 + k) * 64 + c];
    else if (T == 10)  v = sW1[(1088 + k) * 64 + c];
  } else if (tile == 41) v = sW2[k * 64 + c];
  else                   v = sW3[k * 1088 + (tile - 42) * 64 + c];
  wout[gid] = f2bf(v);
}

#define STAGE_W(srcbase) do { const ushort* _s = (srcbase);                      \
  _Pragma("unroll") for (int rr = 0; rr < 2; ++rr) {                             \
    const int idx_ = t + 256 * rr; const int c_ = idx_ >> 3, ko_ = idx_ & 7;     \
    *(short8v*)&Wl[c_ * STX + ko_ * 8] = *(const short8v*)&_s[c_ * 64 + ko_ * 8];\
  } } while (0)

#define MFMA_K64() do {                                                          \
  _Pragma("unroll") for (int kb = 0; kb < 2; ++kb) {                             \
    const bf16x8 af_ = *(const bf16x8*)&Xl[(w * 16 + ll) * STX + kb * 32 + lh * 8]; \
    acc[0] = __builtin_amdgcn_mfma_f32_16x16x32_bf16(af_,                        \
        *(const bf16x8*)&Wl[(     ll) * STX + kb * 32 + lh * 8], acc[0], 0, 0, 0); \
    acc[1] = __builtin_amdgcn_mfma_f32_16x16x32_bf16(af_,                        \
        *(const bf16x8*)&Wl[(16 + ll) * STX + kb * 32 + lh * 8], acc[1], 0, 0, 0); \
    acc[2] = __builtin_amdgcn_mfma_f32_16x16x32_bf16(af_,                        \
        *(const bf16x8*)&Wl[(32 + ll) * STX + kb * 32 + lh * 8], acc[2], 0, 0, 0); \
    acc[3] = __builtin_amdgcn_mfma_f32_16x16x32_bf16(af_,                        \
        *(const bf16x8*)&Wl[(48 + ll) * STX + kb * 32 + lh * 8], acc[3], 0, 0, 0); \
  } } while (0)

#define ZERO_ACC() do { _Pragma("unroll") for (int q = 0; q < 4; ++q)            \
    acc[q] = (f32x4){0.f, 0.f, 0.f, 0.f}; } while (0)

// LDS carve (53152 B -> 3 blocks/CU):
//  0      smF   [64*97] f32                 24832
//  24832  Xl    [64*72] bf16                 9216
//  34048  Wl    [64*72] bf16                 9216
//  43264  R1: WembL(f32,embed) / red(f32,postG1) / C2h(bf16 [64][65],G3)  8320
//  51584  R2: tabL(ushort[528],G1) / iFn(f32[64],postG1..G3)              1056
//  52640  es_s int[64] | e0s ushort[64] | e1s ushort[64]                   512
#define LDS_BYTES 53152

__global__ __launch_bounds__(256, 3)
void sgnn_edge(const float* __restrict__ f, const float* __restrict__ s,
               const float* __restrict__ edge_f, const float* __restrict__ edge_s,
               const float* __restrict__ Wemb,
               const float* __restrict__ b1, const float* __restrict__ b2,
               const float* __restrict__ b3,
               const ushort* __restrict__ wbf, const ushort* __restrict__ tab_g,
               const int* __restrict__ eidx, const int* __restrict__ sorted,
               float* __restrict__ fc_sum, float* __restrict__ sc_sum) {
  __shared__ __align__(16) char sbuf[LDS_BYTES];
  float*  smF  = (float*)sbuf;
  ushort* Xl   = (ushort*)(sbuf + 24832);
  ushort* Wl   = (ushort*)(sbuf + 34048);
  float*  R1f  = (float*)(sbuf + 43264);   // WembL / red
  ushort* C2h  = (ushort*)(sbuf + 43264);  // bf16 [64][65]
  ushort* tabL = (ushort*)(sbuf + 51584);
  float*  iFn  = (float*)(sbuf + 51584);   // overlays tab after GEMM1
  int*    es_s = (int*)(sbuf + 52640);
  ushort* e0s  = (ushort*)(sbuf + 52896);
  ushort* e1s  = (ushort*)(sbuf + 53024);

  const int t = threadIdx.x, j = t & 63, w = t >> 6, eb = w * 16;
  const int lh = j >> 4, ll = j & 15;
  const int bid = blockIdx.x;
  float* WembL = R1f;
  float* red   = R1f;

  if (t < 64) {
    const int e = sorted[bid * 64 + t];
    es_s[t] = e;
    e0s[t] = (ushort)eidx[e];
    e1s[t] = (ushort)eidx[NE + e];
  }
  for (int idx = t; idx < NTRI; idx += 256) tabL[idx] = tab_g[idx];
  for (int idx = t; idx < 65 * 32; idx += 256) WembL[idx] = Wemb[idx];
  __syncthreads();

  // ---- embed (f32): smF[le][i*32+a] = concat(f[e0],f[e1],edge_f) @ Wemb1 ----
  #pragma unroll 1
  for (int r = 0; r < 24; ++r) {
    const int out = t + 256 * r;
    const int jj = out & 31;
    const int i = (out >> 5) % 3;
    const int le = out / 96;
    const float* base0 = f + e0s[le] * 96 + i * 32;
    const float* base1 = f + e1s[le] * 96 + i * 32;
    float a = 0.f;
    #pragma unroll
    for (int kq = 0; kq < 8; ++kq) {
      const float4 v = *(const float4*)(base0 + kq * 4);
      a = fmaf(v.x, WembL[(kq * 4 + 0) * 32 + jj], a);
      a = fmaf(v.y, WembL[(kq * 4 + 1) * 32 + jj], a);
      a = fmaf(v.z, WembL[(kq * 4 + 2) * 32 + jj], a);
      a = fmaf(v.w, WembL[(kq * 4 + 3) * 32 + jj], a);
    }
    #pragma unroll
    for (int kq = 0; kq < 8; ++kq) {
      const float4 v = *(const float4*)(base1 + kq * 4);
      a = fmaf(v.x, WembL[(32 + kq * 4 + 0) * 32 + jj], a);
      a = fmaf(v.y, WembL[(32 + kq * 4 + 1) * 32 + jj], a);
      a = fmaf(v.z, WembL[(32 + kq * 4 + 2) * 32 + jj], a);
      a = fmaf(v.w, WembL[(32 + kq * 4 + 3) * 32 + jj], a);
    }
    a = fmaf(edge_f[es_s[le] * 3 + i], WembL[64 * 32 + jj], a);
    smF[le * SF + i * 32 + jj] = a;
  }

  f32x4 acc[4];
  ZERO_ACC();
  float sumsq = 0.f;

  // ---- GEMM1: 12 K-stages of 64 (528 tri | edge_s tail | s0 | s1 | edge_s) ----
  #pragma unroll 1
  for (int T = 0; T < 12; ++T) {
    __syncthreads();
    {
      const float* fr = smF + j * SF;
      #pragma unroll 1
      for (int m = 0; m < 16; ++m) {
        const int kk = w + m * 4;   // uniform across the wave's 64 lanes
        float v;
        if (T < 8 || (T == 8 && kk < 16)) {
          const int tb = tabL[T * 64 + kk];     // broadcast read
          const int a_ = tb & 31, b_ = (tb >> 8) & 31;
          v = fmaf(fr[a_], fr[b_],
              fmaf(fr[32 + a_], fr[32 + b_], fr[64 + a_] * fr[64 + b_]));
          const float wsel = (tb & 0x8000) ? 2.f : 1.f;
          sumsq = fmaf(v * wsel, v, sumsq);
        } else if (T == 8)  v = (kk < 20) ? edge_s[es_s[j] * 68 + 64 + (kk - 16)] : 0.f;
        else if (T == 9)    v = s[e0s[j] * 64 + kk];
        else if (T == 10)   v = s[e1s[j] * 64 + kk];
        else                v = edge_s[es_s[j] * 68 + kk];
        Xl[j * STX + kk] = f2bf(v);
      }
    }
    STAGE_W(wbf + T * 4096);
    __syncthreads();
    MFMA_K64();
  }

  // ---- h1 epilogue + Fn reduce + W2 stage ----
  __syncthreads();
  red[w * 64 + j] = sumsq;
  #pragma unroll
  for (int nc = 0; nc < 4; ++nc) {
    const float bv = b1[nc * 16 + ll];
    #pragma unroll
    for (int r = 0; r < 4; ++r)
      Xl[(w * 16 + lh * 4 + r) * STX + nc * 16 + ll] = f2bf(fmaxf(acc[nc][r] + bv, 0.f));
  }
  STAGE_W(wbf + 12 * 4096);
  ZERO_ACC();
  __syncthreads();
  if (t < 64) {
    const float ss = red[t] + red[64 + t] + red[128 + t] + red[192 + t];
    iFn[t] = 1.f / (sqrtf(ss) + 1.f);   // overlays dead tab region
  }

  // ---- GEMM2 ----
  MFMA_K64();
  __syncthreads();
  #pragma unroll
  for (int nc = 0; nc < 4; ++nc) {
    const float bv = b2[nc * 16 + ll];
    #pragma unroll
    for (int r = 0; r < 4; ++r)
      Xl[(w * 16 + lh * 4 + r) * STX + nc * 16 + ll] = f2bf(fmaxf(acc[nc][r] + bv, 0.f));
  }

  // ---- GEMM3 (17 n-tiles) + fused consume ----
  float fcp[48];
  #pragma unroll
  for (int q = 0; q < 48; ++q) fcp[q] = 0.f;

  #pragma unroll 1
  for (int nt = 0; nt < 17; ++nt) {
    __syncthreads();
    STAGE_W(wbf + (13 + nt) * 4096);
    __syncthreads();
    ZERO_ACC();
    MFMA_K64();
    #pragma unroll
    for (int nc = 0; nc < 4; ++nc)
      #pragma unroll
      for (int r = 0; r < 4; ++r)
        C2h[(w * 16 + lh * 4 + r) * 65 + nc * 16 + ll] = f2bf(acc[nc][r]);
    // wave-private rows: no barrier needed before consume
    const float bv = b3[nt * 64 + j];
    if (nt < 16) {
      const int a_ = nt * 2 + (j >> 5);
      #pragma unroll
      for (int m = 0; m < 16; ++m) {
        const float cv = (bf2f(C2h[(eb + m) * 65 + j]) + bv) * iFn[eb + m];
        const float* fr = smF + (eb + m) * SF;
        fcp[m * 3 + 0] = fmaf(fr[a_],      cv, fcp[m * 3 + 0]);
        fcp[m * 3 + 1] = fmaf(fr[32 + a_], cv, fcp[m * 3 + 1]);
        fcp[m * 3 + 2] = fmaf(fr[64 + a_], cv, fcp[m * 3 + 2]);
      }
    } else {
      float run = 0.f;
      #pragma unroll 1
      for (int m = 0; m < 16; ++m) {
        run += (bf2f(C2h[(eb + m) * 65 + j]) + bv) * iFn[eb + m];
        const int e0 = e0s[eb + m];
        if (m == 15 || e0s[eb + m + 1] != e0) {
          atomicAdd(sc_sum + e0 * 64 + j, run);
          run = 0.f;
        }
      }
    }
  }

  // ---- fc: pair-reduce (j, j^32), run-compressed atomics ----
  {
    const int b_ = j & 31;
    float r0 = 0.f, r1 = 0.f, r2 = 0.f;
    #pragma unroll 1
    for (int m = 0; m < 16; ++m) {
      const int e0 = e0s[eb + m];
      float v0 = fcp[m * 3 + 0]; v0 += __shfl_xor(v0, 32);
      float v1 = fcp[m * 3 + 1]; v1 += __shfl_xor(v1, 32);
      float v2 = fcp[m * 3 + 2]; v2 += __shfl_xor(v2, 32);
      r0 += v0; r1 += v1; r2 += v2;
      if (m == 15 || e0s[eb + m + 1] != e0) {
        if (j < 32) {
          atomicAdd(fc_sum + e0 * 96 +      b_, r0);
          atomicAdd(fc_sum + e0 * 96 + 32 + b_, r1);
          atomicAdd(fc_sum + e0 * 96 + 64 + b_, r2);
        }
        r0 = r1 = r2 = 0.f;
      }
    }
  }
}

// sums -> means
__global__ __launch_bounds__(256)
void sgnn_norm(float* __restrict__ fcm, float* __restrict__ scm,
               const int* __restrict__ deg) {
  const int idx = blockIdx.x * 256 + threadIdx.x;
  if (idx >= NN * 160) return;
  const int n = idx / 160, c = idx % 160;
  const float ic = 1.f / fmaxf((float)deg[n], 1.f);
  if (c < 96) fcm[n * 96 + c] *= ic;
  else        scm[n * 64 + (c - 96)] *= ic;
}

__global__ __launch_bounds__(256, 3)
void sgnn_node(const float* __restrict__ f, const float* __restrict__ s,
               const float* __restrict__ Wemb,
               const float* __restrict__ b1, const float* __restrict__ b2,
               const float* __restrict__ b3,
               const ushort* __restrict__ wbf, const ushort* __restrict__ tab_g,
               const float* __restrict__ fcm, const float* __restrict__ scm,
               float* __restrict__ of, float* __restrict__ os) {
  __shared__ __align__(16) char sbuf[LDS_BYTES];
  float*  smF  = (float*)sbuf;
  ushort* Xl   = (ushort*)(sbuf + 24832);
  ushort* Wl   = (ushort*)(sbuf + 34048);
  float*  R1f  = (float*)(sbuf + 43264);
  ushort* C2h  = (ushort*)(sbuf + 43264);
  ushort* tabL = (ushort*)(sbuf + 51584);
  float*  iFn  = (float*)(sbuf + 51584);

  const int t = threadIdx.x, j = t & 63, w = t >> 6, eb = w * 16;
  const int lh = j >> 4, ll = j & 15;
  const int nbase = blockIdx.x * 64;
  float* WembL = R1f;
  float* red   = R1f;

  for (int idx = t; idx < NTRI; idx += 256) tabL[idx] = tab_g[idx];
  for (int idx = t; idx < 64 * 32; idx += 256) WembL[idx] = Wemb[idx];
  __syncthreads();

  // ---- embed: tf = concat(f, f_c_mean) @ Wemb2 ----
  #pragma unroll 1
  for (int r = 0; r < 24; ++r) {
    const int out = t + 256 * r;
    const int jj = out & 31;
    const int i = (out >> 5) % 3;
    const int le = out / 96;
    const int nc = min(nbase + le, NN - 1);
    const float* base0 = f + nc * 96 + i * 32;
    const float* basec = fcm + nc * 96 + i * 32;
    float a = 0.f;
    #pragma unroll
    for (int kq = 0; kq < 8; ++kq) {
      const float4 v = *(const float4*)(base0 + kq * 4);
      a = fmaf(v.x, WembL[(kq * 4 + 0) * 32 + jj], a);
      a = fmaf(v.y, WembL[(kq * 4 + 1) * 32 + jj], a);
      a = fmaf(v.z, WembL[(kq * 4 + 2) * 32 + jj], a);
      a = fmaf(v.w, WembL[(kq * 4 + 3) * 32 + jj], a);
    }
    #pragma unroll
    for (int kq = 0; kq < 8; ++kq) {
      const float4 v = *(const float4*)(basec + kq * 4);
      a = fmaf(v.x, WembL[(32 + kq * 4 + 0) * 32 + jj], a);
      a = fmaf(v.y, WembL[(32 + kq * 4 + 1) * 32 + jj], a);
      a = fmaf(v.z, WembL[(32 + kq * 4 + 2) * 32 + jj], a);
      a = fmaf(v.w, WembL[(32 + kq * 4 + 3) * 32 + jj], a);
    }
    smF[le * SF + i * 32 + jj] = a;
  }

  f32x4 acc[4];
  ZERO_ACC();
  float sumsq = 0.f;

  // ---- GEMM1: 11 K-stages (528 tri | s | s_c) ----
  #pragma unroll 1
  for (int T = 0; T < 11; ++T) {
    __syncthreads();
    {
      const int nc = min(nbase + j, NN - 1);
      const float* fr = smF + j * SF;
      #pragma unroll 1
      for (int m = 0; m < 16; ++m) {
        const int kk = w + m * 4;
        float v;
        if (T < 8 || (T == 8 && kk < 16)) {
          const int tb = tabL[T * 64 + kk];
          const int a_ = tb & 31, b_ = (tb >> 8) & 31;
          v = fmaf(fr[a_], fr[b_],
              fmaf(fr[32 + a_], fr[32 + b_], fr[64 + a_] * fr[64 + b_]));
          const float wsel = (tb & 0x8000) ? 2.f : 1.f;
          sumsq = fmaf(v * wsel, v, sumsq);
        } else if (T == 8)  v = 0.f;
        else if (T == 9)    v = s[nc * 64 + kk];
        else                v = scm[nc * 64 + kk];
        Xl[j * STX + kk] = f2bf(v);
      }
    }
    STAGE_W(wbf + (30 + T) * 4096);
    __syncthreads();
    MFMA_K64();
  }

  __syncthreads();
  red[w * 64 + j] = sumsq;
  #pragma unroll
  for (int nc = 0; nc < 4; ++nc) {
    const float bv = b1[nc * 16 + ll];
    #pragma unroll
    for (int r = 0; r < 4; ++r)
      Xl[(w * 16 + lh * 4 + r) * STX + nc * 16 + ll] = f2bf(fmaxf(acc[nc][r] + bv, 0.f));
  }
  STAGE_W(wbf + 41 * 4096);
  ZERO_ACC();
  __syncthreads();
  if (t < 64) {
    const float ss = red[t] + red[64 + t] + red[128 + t] + red[192 + t];
    iFn[t] = 1.f / (sqrtf(ss) + 1.f);
  }

  MFMA_K64();
  __syncthreads();
  #pragma unroll
  for (int nc = 0; nc < 4; ++nc) {
    const float bv = b2[nc * 16 + ll];
    #pragma unroll
    for (int r = 0; r < 4; ++r)
      Xl[(w * 16 + lh * 4 + r) * STX + nc * 16 + ll] = f2bf(fmaxf(acc[nc][r] + bv, 0.f));
  }

  float fcp[48];
  #pragma unroll
  for (int q = 0; q < 48; ++q) fcp[q] = 0.f;

  #pragma unroll 1
  for (int nt = 0; nt < 17; ++nt) {
    __syncthreads();
    STAGE_W(wbf + (42 + nt) * 4096);
    __syncthreads();
    ZERO_ACC();
    MFMA_K64();
    #pragma unroll
    for (int nc = 0; nc < 4; ++nc)
      #pragma unroll
      for (int r = 0; r < 4; ++r)
        C2h[(w * 16 + lh * 4 + r) * 65 + nc * 16 + ll] = f2bf(acc[nc][r]);
    const float bv = b3[nt * 64 + j];
    if (nt < 16) {
      const int a_ = nt * 2 + (j >> 5);
      #pragma unroll
      for (int m = 0; m < 16; ++m) {
        const float cv = (bf2f(C2h[(eb + m) * 65 + j]) + bv) * iFn[eb + m];
        const float* fr = smF + (eb + m) * SF;
        fcp[m * 3 + 0] = fmaf(fr[a_],      cv, fcp[m * 3 + 0]);
        fcp[m * 3 + 1] = fmaf(fr[32 + a_], cv, fcp[m * 3 + 1]);
        fcp[m * 3 + 2] = fmaf(fr[64 + a_], cv, fcp[m * 3 + 2]);
      }
    } else {
      #pragma unroll 1
      for (int m = 0; m < 16; ++m) {
        const int n_m = nbase + eb + m;
        const float cv = (bf2f(C2h[(eb + m) * 65 + j]) + bv) * iFn[eb + m];
        if (n_m < NN) os[n_m * 64 + j] = cv + s[n_m * 64 + j];
      }
    }
  }

  {
    const int b_ = j & 31;
    #pragma unroll 1
    for (int m = 0; m < 16; ++m) {
      const int n_m = nbase + eb + m;
      #pragma unroll
      for (int i = 0; i < 3; ++i) {
        float v = fcp[m * 3 + i];
        v += __shfl_xor(v, 32);
        if (j < 32 && n_m < NN)
          of[n_m * 96 + i * 32 + b_] = v + f[n_m * 96 + i * 32 + b_];
      }
    }
  }
}

extern "C" void kernel_launch(void* const* d_in, const int* in_sizes, int n_in,
                              void* d_out, int out_size, void* d_ws, size_t ws_size,
                              hipStream_t stream) {
  const float* f      = (const float*)d_in[0];
  const float* s      = (const float*)d_in[1];
  const float* edge_f = (const float*)d_in[2];
  const float* edge_s = (const float*)d_in[3];
  const float* Wemb1  = (const float*)d_in[4];
  const float* nW1 = (const float*)d_in[5];
  const float* nb1 = (const float*)d_in[6];
  const float* nW2 = (const float*)d_in[7];
  const float* nb2 = (const float*)d_in[8];
  const float* nW3 = (const float*)d_in[9];
  const float* nb3 = (const float*)d_in[10];
  const float* Wemb2 = (const float*)d_in[11];
  const float* sW1 = (const float*)d_in[12];
  const float* sb1 = (const float*)d_in[13];
  const float* sW2 = (const float*)d_in[14];
  const float* sb2 = (const float*)d_in[15];
  const float* sW3 = (const float*)d_in[16];
  const float* sb3 = (const float*)d_in[17];
  const int* eidx  = (const int*)d_in[18];

  float* of = (float*)d_out;               // [NN*96] ; aliases fc mean
  float* os = of + (size_t)NN * 96;        // [NN*64] ; aliases sc mean

  // ws: deg[NN] | cursor[NN] | sorted[NE] | wbf[59*4096 bf16] | tab[528]
  int* deg    = (int*)d_ws;
  int* cursor = deg + NN;
  int* sorted = cursor + NN;
  ushort* wbf = (ushort*)(sorted + NE);
  ushort* tab = wbf + 59 * 4096;

  hipMemsetAsync(deg, 0, (size_t)NN * 4, stream);
  hipMemsetAsync(d_out, 0, (size_t)NN * 160 * 4, stream);

  hipLaunchKernelGGL(sgnn_wconv, dim3((59 * 4096 + NTRI + 255) / 256), dim3(256),
                     0, stream, nW1, nW2, nW3, sW1, sW2, sW3, wbf, tab);
  hipLaunchKernelGGL(sgnn_hist, dim3((NE + 255) / 256), dim3(256), 0, stream,
                     eidx, deg);
  hipLaunchKernelGGL(sgnn_scan, dim3(1), dim3(1024), 0, stream, deg, cursor);
  hipLaunchKernelGGL(sgnn_scatter, dim3((NE + 255) / 256), dim3(256), 0, stream,
                     eidx, cursor, sorted);
  hipLaunchKernelGGL(sgnn_edge, dim3(NE / 64), dim3(256), 0, stream,
                     f, s, edge_f, edge_s, Wemb1, nb1, nb2, nb3,
                     wbf, tab, eidx, sorted, of /*fc_sum*/, os /*sc_sum*/);
  hipLaunchKernelGGL(sgnn_norm, dim3((NN * 160 + 255) / 256), dim3(256), 0, stream,
                     of, os, deg);
  hipLaunchKernelGGL(sgnn_node, dim3((NN + 63) / 64), dim3(256), 0, stream,
                     f, s, Wemb2, sb1, sb2, sb3,
                     wbf, tab, of /*fcm*/, os /*scm*/, of, os);
}

// Round 6
// 341.243 us; speedup vs baseline: 4.4401x; 1.3601x over previous
//
#include <hip/hip_runtime.h>
#include <math.h>

#define NN 10000
#define NE 80000
#define SF 97    // smF row stride (f32): stride%32==1 -> conflict-free per-lane rows
#define STX 72   // bf16 tile row stride (144B rows, 16B-aligned)
#define NTRI 528 // 32*33/2 unique Gram entries

typedef __attribute__((ext_vector_type(8))) __bf16 bf16x8;
typedef __attribute__((ext_vector_type(8))) short short8v;
typedef __attribute__((ext_vector_type(4))) float f32x4;

__device__ __forceinline__ ushort f2bf(float x) {
  union { float f; unsigned u; } v; v.f = x;
  unsigned r = v.u + 0x7FFFu + ((v.u >> 16) & 1u);
  return (ushort)(r >> 16);
}
__device__ __forceinline__ float bf2f(ushort u) {
  union { unsigned u; float f; } v; v.u = (unsigned)u << 16;
  return v.f;
}
__device__ __forceinline__ void tri_ab(int k, int& a, int& b) {
  int aa = 0, rem = k;
  while (rem >= 32 - aa) { rem -= 32 - aa; ++aa; }
  a = aa; b = aa + rem;
}

// ---- sort edges by e0 (verified R2/R3) ----
__global__ __launch_bounds__(256)
void sgnn_hist(const int* __restrict__ eidx, int* __restrict__ deg) {
  const int e = blockIdx.x * 256 + threadIdx.x;
  if (e < NE) atomicAdd(deg + eidx[e], 1);
}

__global__ __launch_bounds__(1024)
void sgnn_scan(const int* __restrict__ deg, int* __restrict__ cursor,
               int* __restrict__ start) {
  __shared__ int sm[1024];
  __shared__ int carry;
  const int t = threadIdx.x;
  if (t == 0) carry = 0;
  __syncthreads();
  for (int base = 0; base < NN; base += 1024) {
    const int i = base + t;
    const int v = (i < NN) ? deg[i] : 0;
    sm[t] = v;
    __syncthreads();
    #pragma unroll
    for (int d = 1; d < 1024; d <<= 1) {
      const int add = (t >= d) ? sm[t - d] : 0;
      __syncthreads();
      sm[t] += add;
      __syncthreads();
    }
    const int excl = carry + sm[t] - v;
    if (i < NN) { cursor[i] = excl; start[i] = excl; }
    __syncthreads();
    if (t == 1023) carry += sm[1023];
    __syncthreads();
  }
}

__global__ __launch_bounds__(256)
void sgnn_scatter(const int* __restrict__ eidx, int* __restrict__ cursor,
                  int* __restrict__ sorted) {
  const int e = blockIdx.x * 256 + threadIdx.x;
  if (e < NE) {
    const int p = atomicAdd(cursor + eidx[e], 1);
    sorted[p] = e;
  }
}

// ---- weight convert (verified R4): f32 -> blocked bf16, W1 K-folded symmetric ----
__global__ __launch_bounds__(256)
void sgnn_wconv(const float* __restrict__ nW1, const float* __restrict__ nW2,
                const float* __restrict__ nW3, const float* __restrict__ sW1,
                const float* __restrict__ sW2, const float* __restrict__ sW3,
                ushort* __restrict__ wout, ushort* __restrict__ tab) {
  const int gid = blockIdx.x * 256 + threadIdx.x;
  if (gid >= 59 * 4096) {
    const int k = gid - 59 * 4096;
    if (k < NTRI) {
      int a, b; tri_ab(k, a, b);
      tab[k] = (ushort)(a | (b << 8) | ((a != b) ? 0x8000 : 0));
    }
    return;
  }
  const int tile = gid >> 12, idx = gid & 4095;
  const int c = idx >> 6, k = idx & 63;
  float v = 0.f;
  if (tile < 12) {
    const int T = tile;
    if (T < 8 || (T == 8 && k < 16)) {
      const int ktri = T * 64 + k;
      if (ktri < NTRI) {
        int a, b; tri_ab(ktri, a, b);
        v = nW1[(a * 32 + b) * 64 + c];
        if (a != b) v += nW1[(b * 32 + a) * 64 + c];
      }
    } else if (T == 8) { if (k < 20) v = nW1[(1216 + (k - 16)) * 64 + c]; }
    else if (T == 9)   v = nW1[(1024 + k) * 64 + c];
    else if (T == 10)  v = nW1[(1088 + k) * 64 + c];
    else               v = nW1[(1152 + k) * 64 + c];
  } else if (tile == 12) v = nW2[k * 64 + c];
  else if (tile < 30)    v = nW3[k * 1088 + (tile - 13) * 64 + c];
  else if (tile < 41) {
    const int T = tile - 30;
    if (T < 8 || (T == 8 && k < 16)) {
      const int ktri = T * 64 + k;
      if (ktri < NTRI) {
        int a, b; tri_ab(ktri, a, b);
        v = sW1[(a * 32 + b) * 64 + c];
        if (a != b) v += sW1[(b * 32 + a) * 64 + c];
      }
    } else if (T == 9) v = sW1[(1024 + k) * 64 + c];
    else if (T == 10)  v = sW1[(1088 + k) * 64 + c];
  } else if (tile == 41) v = sW2[k * 64 + c];
  else                   v = sW3[k * 1088 + (tile - 42) * 64 + c];
  wout[gid] = f2bf(v);
}

#define STAGE_W(srcbase) do { const ushort* _s = (srcbase);                      \
  _Pragma("unroll") for (int rr = 0; rr < 2; ++rr) {                             \
    const int idx_ = t + 256 * rr; const int c_ = idx_ >> 3, ko_ = idx_ & 7;     \
    *(short8v*)&Wl[c_ * STX + ko_ * 8] = *(const short8v*)&_s[c_ * 64 + ko_ * 8];\
  } } while (0)

#define MFMA_K64() do {                                                          \
  _Pragma("unroll") for (int kb = 0; kb < 2; ++kb) {                             \
    const bf16x8 af_ = *(const bf16x8*)&Xl[(w * 16 + ll) * STX + kb * 32 + lh * 8]; \
    acc[0] = __builtin_amdgcn_mfma_f32_16x16x32_bf16(af_,                        \
        *(const bf16x8*)&Wl[(     ll) * STX + kb * 32 + lh * 8], acc[0], 0, 0, 0); \
    acc[1] = __builtin_amdgcn_mfma_f32_16x16x32_bf16(af_,                        \
        *(const bf16x8*)&Wl[(16 + ll) * STX + kb * 32 + lh * 8], acc[1], 0, 0, 0); \
    acc[2] = __builtin_amdgcn_mfma_f32_16x16x32_bf16(af_,                        \
        *(const bf16x8*)&Wl[(32 + ll) * STX + kb * 32 + lh * 8], acc[2], 0, 0, 0); \
    acc[3] = __builtin_amdgcn_mfma_f32_16x16x32_bf16(af_,                        \
        *(const bf16x8*)&Wl[(48 + ll) * STX + kb * 32 + lh * 8], acc[3], 0, 0, 0); \
  } } while (0)

#define ZERO_ACC() do { _Pragma("unroll") for (int q = 0; q < 4; ++q)            \
    acc[q] = (f32x4){0.f, 0.f, 0.f, 0.f}; } while (0)

// LDS carve (53152 B -> 3 blocks/CU)
#define LDS_BYTES 53152

__global__ __launch_bounds__(256, 3)
void sgnn_edge(const float* __restrict__ f, const float* __restrict__ s,
               const float* __restrict__ edge_f, const float* __restrict__ edge_s,
               const float* __restrict__ Wemb,
               const float* __restrict__ b1, const float* __restrict__ b2,
               const float* __restrict__ b3,
               const ushort* __restrict__ wbf, const ushort* __restrict__ tab_g,
               const int* __restrict__ eidx, const int* __restrict__ sorted,
               const int* __restrict__ start_g, const int* __restrict__ deg_g,
               float* __restrict__ fc_sum, float* __restrict__ sc_sum) {
  __shared__ __align__(16) char sbuf[LDS_BYTES];
  float*  smF  = (float*)sbuf;
  ushort* Xl   = (ushort*)(sbuf + 24832);
  ushort* Wl   = (ushort*)(sbuf + 34048);
  float*  R1f  = (float*)(sbuf + 43264);   // WembL / red
  ushort* C2h  = (ushort*)(sbuf + 43264);  // bf16 [64][65]
  ushort* tabL = (ushort*)(sbuf + 51584);
  float*  iFn  = (float*)(sbuf + 51584);
  int*    es_s = (int*)(sbuf + 52640);
  ushort* e0s  = (ushort*)(sbuf + 52896);
  ushort* e1s  = (ushort*)(sbuf + 53024);
  // flush-phase overlays on dead Xl region:
  float*  fcpart = (float*)(sbuf + 24832);          // [8][96]
  float*  scpart = (float*)(sbuf + 24832 + 3072);   // [8][64]
  int*    snode  = (int*)(sbuf + 24832 + 5120);     // [8]
  int*    sst    = (int*)(sbuf + 24832 + 5152);     // [8]
  int*    sdg    = (int*)(sbuf + 24832 + 5184);     // [8]

  const int t = threadIdx.x, j = t & 63, w = t >> 6, eb = w * 16;
  const int lh = j >> 4, ll = j & 15;
  const int bid = blockIdx.x;
  float* WembL = R1f;
  float* red   = R1f;

  if (t < 64) {
    const int e = sorted[bid * 64 + t];
    es_s[t] = e;
    e0s[t] = (ushort)eidx[e];
    e1s[t] = (ushort)eidx[NE + e];
  }
  for (int idx = t; idx < NTRI; idx += 256) tabL[idx] = tab_g[idx];
  for (int idx = t; idx < 65 * 32; idx += 256) WembL[idx] = Wemb[idx];
  __syncthreads();

  // per-row node extent (lane m<16 holds row eb+m's start/deg)
  int str = 0, dgr = 0;
  if (j < 16) {
    const int n_ = e0s[eb + j];
    str = start_g[n_];
    dgr = deg_g[n_];
  }

  // ---- embed (f32) ----
  #pragma unroll 1
  for (int r = 0; r < 24; ++r) {
    const int out = t + 256 * r;
    const int jj = out & 31;
    const int i = (out >> 5) % 3;
    const int le = out / 96;
    const float* base0 = f + e0s[le] * 96 + i * 32;
    const float* base1 = f + e1s[le] * 96 + i * 32;
    float a = 0.f;
    #pragma unroll
    for (int kq = 0; kq < 8; ++kq) {
      const float4 v = *(const float4*)(base0 + kq * 4);
      a = fmaf(v.x, WembL[(kq * 4 + 0) * 32 + jj], a);
      a = fmaf(v.y, WembL[(kq * 4 + 1) * 32 + jj], a);
      a = fmaf(v.z, WembL[(kq * 4 + 2) * 32 + jj], a);
      a = fmaf(v.w, WembL[(kq * 4 + 3) * 32 + jj], a);
    }
    #pragma unroll
    for (int kq = 0; kq < 8; ++kq) {
      const float4 v = *(const float4*)(base1 + kq * 4);
      a = fmaf(v.x, WembL[(32 + kq * 4 + 0) * 32 + jj], a);
      a = fmaf(v.y, WembL[(32 + kq * 4 + 1) * 32 + jj], a);
      a = fmaf(v.z, WembL[(32 + kq * 4 + 2) * 32 + jj], a);
      a = fmaf(v.w, WembL[(32 + kq * 4 + 3) * 32 + jj], a);
    }
    a = fmaf(edge_f[es_s[le] * 3 + i], WembL[64 * 32 + jj], a);
    smF[le * SF + i * 32 + jj] = a;
  }

  f32x4 acc[4];
  ZERO_ACC();
  float sumsq = 0.f;

  // ---- GEMM1: 12 K-stages ----
  #pragma unroll 1
  for (int T = 0; T < 12; ++T) {
    __syncthreads();
    {
      const float* fr = smF + j * SF;
      #pragma unroll 1
      for (int m = 0; m < 16; ++m) {
        const int kk = w + m * 4;
        float v;
        if (T < 8 || (T == 8 && kk < 16)) {
          const int tb = tabL[T * 64 + kk];
          const int a_ = tb & 31, b_ = (tb >> 8) & 31;
          v = fmaf(fr[a_], fr[b_],
              fmaf(fr[32 + a_], fr[32 + b_], fr[64 + a_] * fr[64 + b_]));
          const float wsel = (tb & 0x8000) ? 2.f : 1.f;
          sumsq = fmaf(v * wsel, v, sumsq);
        } else if (T == 8)  v = (kk < 20) ? edge_s[es_s[j] * 68 + 64 + (kk - 16)] : 0.f;
        else if (T == 9)    v = s[e0s[j] * 64 + kk];
        else if (T == 10)   v = s[e1s[j] * 64 + kk];
        else                v = edge_s[es_s[j] * 68 + kk];
        Xl[j * STX + kk] = f2bf(v);
      }
    }
    STAGE_W(wbf + T * 4096);
    __syncthreads();
    MFMA_K64();
  }

  // ---- h1 epilogue + Fn reduce + W2 stage ----
  __syncthreads();
  red[w * 64 + j] = sumsq;
  #pragma unroll
  for (int nc = 0; nc < 4; ++nc) {
    const float bv = b1[nc * 16 + ll];
    #pragma unroll
    for (int r = 0; r < 4; ++r)
      Xl[(w * 16 + lh * 4 + r) * STX + nc * 16 + ll] = f2bf(fmaxf(acc[nc][r] + bv, 0.f));
  }
  STAGE_W(wbf + 12 * 4096);
  ZERO_ACC();
  __syncthreads();
  if (t < 64) {
    const float ss = red[t] + red[64 + t] + red[128 + t] + red[192 + t];
    iFn[t] = 1.f / (sqrtf(ss) + 1.f);
  }

  // ---- GEMM2 ----
  MFMA_K64();
  __syncthreads();
  #pragma unroll
  for (int nc = 0; nc < 4; ++nc) {
    const float bv = b2[nc * 16 + ll];
    #pragma unroll
    for (int r = 0; r < 4; ++r)
      Xl[(w * 16 + lh * 4 + r) * STX + nc * 16 + ll] = f2bf(fmaxf(acc[nc][r] + bv, 0.f));
  }

  // ---- GEMM3 (17 n-tiles) + fused consume ----
  float fcp[48];
  #pragma unroll
  for (int q = 0; q < 48; ++q) fcp[q] = 0.f;
  float csv[16];

  #pragma unroll 1
  for (int nt = 0; nt < 17; ++nt) {
    __syncthreads();
    STAGE_W(wbf + (13 + nt) * 4096);
    __syncthreads();
    ZERO_ACC();
    MFMA_K64();
    #pragma unroll
    for (int nc = 0; nc < 4; ++nc)
      #pragma unroll
      for (int r = 0; r < 4; ++r)
        C2h[(w * 16 + lh * 4 + r) * 65 + nc * 16 + ll] = f2bf(acc[nc][r]);
    // wave-private rows: no barrier needed before consume
    const float bv = b3[nt * 64 + j];
    if (nt < 16) {
      const int a_ = nt * 2 + (j >> 5);
      #pragma unroll
      for (int m = 0; m < 16; ++m) {
        const float cv = (bf2f(C2h[(eb + m) * 65 + j]) + bv) * iFn[eb + m];
        const float* fr = smF + (eb + m) * SF;
        fcp[m * 3 + 0] = fmaf(fr[a_],      cv, fcp[m * 3 + 0]);
        fcp[m * 3 + 1] = fmaf(fr[32 + a_], cv, fcp[m * 3 + 1]);
        fcp[m * 3 + 2] = fmaf(fr[64 + a_], cv, fcp[m * 3 + 2]);
      }
    } else {
      #pragma unroll
      for (int m = 0; m < 16; ++m)
        csv[m] = (bf2f(C2h[(eb + m) * 65 + j]) + bv) * iFn[eb + m];
    }
  }

  // ---- flush: complete-run stores, partial runs -> LDS merge -> store/atomic ----
  __syncthreads();                 // all waves done with Xl/Wl/C2h
  if (t < 8) snode[t] = -1;
  __syncthreads();

  {
    float r0 = 0.f, r1 = 0.f, r2 = 0.f, rs = 0.f;
    int runlen = 0;
    const int gwb = bid * 64 + eb;
    #pragma unroll
    for (int m = 0; m < 16; ++m) {
      float v0 = fcp[m * 3 + 0]; v0 += __shfl_xor(v0, 32);
      float v1 = fcp[m * 3 + 1]; v1 += __shfl_xor(v1, 32);
      float v2 = fcp[m * 3 + 2]; v2 += __shfl_xor(v2, 32);
      r0 += v0; r1 += v1; r2 += v2; rs += csv[m];
      ++runlen;
      const int n = e0s[eb + m];
      if (m == 15 || e0s[eb + m + 1] != n) {
        const int st = __shfl(str, m);
        const int dg = __shfl(dgr, m);
        const int g1 = gwb + m, g0 = g1 - runlen + 1;
        if (g0 == st && runlen == dg) {
          // complete node: single writer, plain store
          if (j < 32) {
            fc_sum[n * 96 + j]      = r0;
            fc_sum[n * 96 + 32 + j] = r1;
            fc_sum[n * 96 + 64 + j] = r2;
          }
          sc_sum[n * 64 + j] = rs;
        } else {
          const int slot = (g0 == gwb) ? 2 * w : 2 * w + 1;
          if (j < 32) {
            fcpart[slot * 96 + j]      = r0;
            fcpart[slot * 96 + 32 + j] = r1;
            fcpart[slot * 96 + 64 + j] = r2;
          }
          scpart[slot * 64 + j] = rs;
          if (j == 0) { snode[slot] = n; sst[slot] = st; sdg[slot] = dg; }
        }
        r0 = r1 = r2 = rs = 0.f; runlen = 0;
      }
    }
  }
  __syncthreads();

  if (t < 160) {
    const int ch = t;
    int prevn = -1;
    #pragma unroll 1
    for (int ss = 0; ss < 8; ++ss) {
      const int n = snode[ss];
      if (n < 0) { continue; }
      if (n != prevn) {
        float v = (ch < 96) ? fcpart[ss * 96 + ch] : scpart[ss * 64 + (ch - 96)];
        #pragma unroll 1
        for (int k2 = ss + 1; k2 < 8; ++k2) {
          if (snode[k2] == n)
            v += (ch < 96) ? fcpart[k2 * 96 + ch] : scpart[k2 * 64 + (ch - 96)];
          else if (snode[k2] >= 0) break;
        }
        const bool cib = (sst[ss] >= bid * 64) && (sst[ss] + sdg[ss] <= bid * 64 + 64);
        float* dst = (ch < 96) ? (fc_sum + n * 96 + ch) : (sc_sum + n * 64 + (ch - 96));
        if (cib) *dst = v; else atomicAdd(dst, v);
      }
      prevn = n;
    }
  }
}

// sums -> means
__global__ __launch_bounds__(256)
void sgnn_norm(float* __restrict__ fcm, float* __restrict__ scm,
               const int* __restrict__ deg) {
  const int idx = blockIdx.x * 256 + threadIdx.x;
  if (idx >= NN * 160) return;
  const int n = idx / 160, c = idx % 160;
  const float ic = 1.f / fmaxf((float)deg[n], 1.f);
  if (c < 96) fcm[n * 96 + c] *= ic;
  else        scm[n * 64 + (c - 96)] *= ic;
}

__global__ __launch_bounds__(256, 3)
void sgnn_node(const float* __restrict__ f, const float* __restrict__ s,
               const float* __restrict__ Wemb,
               const float* __restrict__ b1, const float* __restrict__ b2,
               const float* __restrict__ b3,
               const ushort* __restrict__ wbf, const ushort* __restrict__ tab_g,
               const float* __restrict__ fcm, const float* __restrict__ scm,
               float* __restrict__ of, float* __restrict__ os) {
  __shared__ __align__(16) char sbuf[LDS_BYTES];
  float*  smF  = (float*)sbuf;
  ushort* Xl   = (ushort*)(sbuf + 24832);
  ushort* Wl   = (ushort*)(sbuf + 34048);
  float*  R1f  = (float*)(sbuf + 43264);
  ushort* C2h  = (ushort*)(sbuf + 43264);
  ushort* tabL = (ushort*)(sbuf + 51584);
  float*  iFn  = (float*)(sbuf + 51584);

  const int t = threadIdx.x, j = t & 63, w = t >> 6, eb = w * 16;
  const int lh = j >> 4, ll = j & 15;
  const int nbase = blockIdx.x * 64;
  float* WembL = R1f;
  float* red   = R1f;

  for (int idx = t; idx < NTRI; idx += 256) tabL[idx] = tab_g[idx];
  for (int idx = t; idx < 64 * 32; idx += 256) WembL[idx] = Wemb[idx];
  __syncthreads();

  // ---- embed: tf = concat(f, f_c_mean) @ Wemb2 ----
  #pragma unroll 1
  for (int r = 0; r < 24; ++r) {
    const int out = t + 256 * r;
    const int jj = out & 31;
    const int i = (out >> 5) % 3;
    const int le = out / 96;
    const int nc = min(nbase + le, NN - 1);
    const float* base0 = f + nc * 96 + i * 32;
    const float* basec = fcm + nc * 96 + i * 32;
    float a = 0.f;
    #pragma unroll
    for (int kq = 0; kq < 8; ++kq) {
      const float4 v = *(const float4*)(base0 + kq * 4);
      a = fmaf(v.x, WembL[(kq * 4 + 0) * 32 + jj], a);
      a = fmaf(v.y, WembL[(kq * 4 + 1) * 32 + jj], a);
      a = fmaf(v.z, WembL[(kq * 4 + 2) * 32 + jj], a);
      a = fmaf(v.w, WembL[(kq * 4 + 3) * 32 + jj], a);
    }
    #pragma unroll
    for (int kq = 0; kq < 8; ++kq) {
      const float4 v = *(const float4*)(basec + kq * 4);
      a = fmaf(v.x, WembL[(32 + kq * 4 + 0) * 32 + jj], a);
      a = fmaf(v.y, WembL[(32 + kq * 4 + 1) * 32 + jj], a);
      a = fmaf(v.z, WembL[(32 + kq * 4 + 2) * 32 + jj], a);
      a = fmaf(v.w, WembL[(32 + kq * 4 + 3) * 32 + jj], a);
    }
    smF[le * SF + i * 32 + jj] = a;
  }

  f32x4 acc[4];
  ZERO_ACC();
  float sumsq = 0.f;

  // ---- GEMM1: 11 K-stages ----
  #pragma unroll 1
  for (int T = 0; T < 11; ++T) {
    __syncthreads();
    {
      const int nc = min(nbase + j, NN - 1);
      const float* fr = smF + j * SF;
      #pragma unroll 1
      for (int m = 0; m < 16; ++m) {
        const int kk = w + m * 4;
        float v;
        if (T < 8 || (T == 8 && kk < 16)) {
          const int tb = tabL[T * 64 + kk];
          const int a_ = tb & 31, b_ = (tb >> 8) & 31;
          v = fmaf(fr[a_], fr[b_],
              fmaf(fr[32 + a_], fr[32 + b_], fr[64 + a_] * fr[64 + b_]));
          const float wsel = (tb & 0x8000) ? 2.f : 1.f;
          sumsq = fmaf(v * wsel, v, sumsq);
        } else if (T == 8)  v = 0.f;
        else if (T == 9)    v = s[nc * 64 + kk];
        else                v = scm[nc * 64 + kk];
        Xl[j * STX + kk] = f2bf(v);
      }
    }
    STAGE_W(wbf + (30 + T) * 4096);
    __syncthreads();
    MFMA_K64();
  }

  __syncthreads();
  red[w * 64 + j] = sumsq;
  #pragma unroll
  for (int nc = 0; nc < 4; ++nc) {
    const float bv = b1[nc * 16 + ll];
    #pragma unroll
    for (int r = 0; r < 4; ++r)
      Xl[(w * 16 + lh * 4 + r) * STX + nc * 16 + ll] = f2bf(fmaxf(acc[nc][r] + bv, 0.f));
  }
  STAGE_W(wbf + 41 * 4096);
  ZERO_ACC();
  __syncthreads();
  if (t < 64) {
    const float ss = red[t] + red[64 + t] + red[128 + t] + red[192 + t];
    iFn[t] = 1.f / (sqrtf(ss) + 1.f);
  }

  MFMA_K64();
  __syncthreads();
  #pragma unroll
  for (int nc = 0; nc < 4; ++nc) {
    const float bv = b2[nc * 16 + ll];
    #pragma unroll
    for (int r = 0; r < 4; ++r)
      Xl[(w * 16 + lh * 4 + r) * STX + nc * 16 + ll] = f2bf(fmaxf(acc[nc][r] + bv, 0.f));
  }

  float fcp[48];
  #pragma unroll
  for (int q = 0; q < 48; ++q) fcp[q] = 0.f;

  #pragma unroll 1
  for (int nt = 0; nt < 17; ++nt) {
    __syncthreads();
    STAGE_W(wbf + (42 + nt) * 4096);
    __syncthreads();
    ZERO_ACC();
    MFMA_K64();
    #pragma unroll
    for (int nc = 0; nc < 4; ++nc)
      #pragma unroll
      for (int r = 0; r < 4; ++r)
        C2h[(w * 16 + lh * 4 + r) * 65 + nc * 16 + ll] = f2bf(acc[nc][r]);
    const float bv = b3[nt * 64 + j];
    if (nt < 16) {
      const int a_ = nt * 2 + (j >> 5);
      #pragma unroll
      for (int m = 0; m < 16; ++m) {
        const float cv = (bf2f(C2h[(eb + m) * 65 + j]) + bv) * iFn[eb + m];
        const float* fr = smF + (eb + m) * SF;
        fcp[m * 3 + 0] = fmaf(fr[a_],      cv, fcp[m * 3 + 0]);
        fcp[m * 3 + 1] = fmaf(fr[32 + a_], cv, fcp[m * 3 + 1]);
        fcp[m * 3 + 2] = fmaf(fr[64 + a_], cv, fcp[m * 3 + 2]);
      }
    } else {
      #pragma unroll 1
      for (int m = 0; m < 16; ++m) {
        const int n_m = nbase + eb + m;
        const float cv = (bf2f(C2h[(eb + m) * 65 + j]) + bv) * iFn[eb + m];
        if (n_m < NN) os[n_m * 64 + j] = cv + s[n_m * 64 + j];
      }
    }
  }

  {
    const int b_ = j & 31;
    #pragma unroll
    for (int m = 0; m < 16; ++m) {
      const int n_m = nbase + eb + m;
      #pragma unroll
      for (int i = 0; i < 3; ++i) {
        float v = fcp[m * 3 + i];
        v += __shfl_xor(v, 32);
        if (j < 32 && n_m < NN)
          of[n_m * 96 + i * 32 + b_] = v + f[n_m * 96 + i * 32 + b_];
      }
    }
  }
}

extern "C" void kernel_launch(void* const* d_in, const int* in_sizes, int n_in,
                              void* d_out, int out_size, void* d_ws, size_t ws_size,
                              hipStream_t stream) {
  const float* f      = (const float*)d_in[0];
  const float* s      = (const float*)d_in[1];
  const float* edge_f = (const float*)d_in[2];
  const float* edge_s = (const float*)d_in[3];
  const float* Wemb1  = (const float*)d_in[4];
  const float* nW1 = (const float*)d_in[5];
  const float* nb1 = (const float*)d_in[6];
  const float* nW2 = (const float*)d_in[7];
  const float* nb2 = (const float*)d_in[8];
  const float* nW3 = (const float*)d_in[9];
  const float* nb3 = (const float*)d_in[10];
  const float* Wemb2 = (const float*)d_in[11];
  const float* sW1 = (const float*)d_in[12];
  const float* sb1 = (const float*)d_in[13];
  const float* sW2 = (const float*)d_in[14];
  const float* sb2 = (const float*)d_in[15];
  const float* sW3 = (const float*)d_in[16];
  const float* sb3 = (const float*)d_in[17];
  const int* eidx  = (const int*)d_in[18];

  float* of = (float*)d_out;               // [NN*96] ; aliases fc mean
  float* os = of + (size_t)NN * 96;        // [NN*64] ; aliases sc mean

  // ws: deg[NN] | cursor[NN] | start[NN] | sorted[NE] | wbf[59*4096] | tab[528]
  int* deg    = (int*)d_ws;
  int* cursor = deg + NN;
  int* start  = cursor + NN;
  int* sorted = start + NN;
  ushort* wbf = (ushort*)(sorted + NE);
  ushort* tab = wbf + 59 * 4096;

  hipMemsetAsync(deg, 0, (size_t)NN * 4, stream);
  hipMemsetAsync(d_out, 0, (size_t)NN * 160 * 4, stream);

  hipLaunchKernelGGL(sgnn_wconv, dim3((59 * 4096 + NTRI + 255) / 256), dim3(256),
                     0, stream, nW1, nW2, nW3, sW1, sW2, sW3, wbf, tab);
  hipLaunchKernelGGL(sgnn_hist, dim3((NE + 255) / 256), dim3(256), 0, stream,
                     eidx, deg);
  hipLaunchKernelGGL(sgnn_scan, dim3(1), dim3(1024), 0, stream, deg, cursor, start);
  hipLaunchKernelGGL(sgnn_scatter, dim3((NE + 255) / 256), dim3(256), 0, stream,
                     eidx, cursor, sorted);
  hipLaunchKernelGGL(sgnn_edge, dim3(NE / 64), dim3(256), 0, stream,
                     f, s, edge_f, edge_s, Wemb1, nb1, nb2, nb3,
                     wbf, tab, eidx, sorted, start, deg,
                     of /*fc_sum*/, os /*sc_sum*/);
  hipLaunchKernelGGL(sgnn_norm, dim3((NN * 160 + 255) / 256), dim3(256), 0, stream,
                     of, os, deg);
  hipLaunchKernelGGL(sgnn_node, dim3((NN + 63) / 64), dim3(256), 0, stream,
                     f, s, Wemb2, sb1, sb2, sb3,
                     wbf, tab, of /*fcm*/, os /*scm*/, of, os);
}